// Round 1
// baseline (654.786 us; speedup 1.0000x reference)
//
#include <hip/hip_runtime.h>
#include <math.h>

#define NW 4096
#define H 768
#define NC 49152
#define MSW 30
#define E 20
#define M 1024
// P layout: [NW][3*M]; cols 0:1024 start-proj, 1024:2048 end-proj, 2048:3072 attn-proj
#define PCOLS 3072

// ---------------- word_attn = doc @ attn_w + attn_b ----------------
__global__ __launch_bounds__(256) void k_word_attn(const float* __restrict__ doc,
                                                   const float* __restrict__ attn_w,
                                                   const float* __restrict__ attn_b,
                                                   float* __restrict__ word_attn) {
    int row = blockIdx.x * 4 + (threadIdx.x >> 6);
    int lane = threadIdx.x & 63;
    const float* r = doc + (size_t)row * H;
    float s = 0.f;
    #pragma unroll
    for (int j = 0; j < H / 64; ++j) s += r[lane + 64 * j] * attn_w[lane + 64 * j];
    #pragma unroll
    for (int off = 32; off > 0; off >>= 1) s += __shfl_down(s, off);
    if (lane == 0) word_attn[row] = s + attn_b[0];
}

// ---------------- PW[w][m] = width_emb[w] @ W1[2H:2H+E] + mlp1_b ----------------
__global__ __launch_bounds__(256) void k_pw(const float* __restrict__ width_emb,
                                            const float* __restrict__ mlp1_w,
                                            const float* __restrict__ mlp1_b,
                                            float* __restrict__ PW) {
    int w = blockIdx.x;                       // 0..29
    int m = blockIdx.y * 256 + threadIdx.x;   // 0..1023
    float acc = mlp1_b[m];
    #pragma unroll
    for (int e = 0; e < E; ++e)
        acc += width_emb[w * E + e] * mlp1_w[(size_t)(2 * H + e) * M + m];
    PW[w * M + m] = acc;
}

// ---------------- wscore[w] = wmlp2 . relu(width_prior_emb[w] @ wmlp1 + b1) + b2 ----------------
__global__ __launch_bounds__(256) void k_wscore(const float* __restrict__ wp_emb,
                                                const float* __restrict__ w1,
                                                const float* __restrict__ b1,
                                                const float* __restrict__ w2,
                                                const float* __restrict__ b2,
                                                float* __restrict__ wscore) {
    int w = blockIdx.x;
    int tid = threadIdx.x;
    float part = 0.f;
    for (int m = tid; m < M; m += 256) {
        float h = b1[m];
        #pragma unroll
        for (int e = 0; e < E; ++e) h += wp_emb[w * E + e] * w1[e * M + m];
        part += fmaxf(h, 0.f) * w2[m];
    }
    __shared__ float red[256];
    red[tid] = part;
    __syncthreads();
    for (int s = 128; s > 0; s >>= 1) {
        if (tid < s) red[tid] += red[tid + s];
        __syncthreads();
    }
    if (tid == 0) wscore[w] = red[0] + b2[0];
}

// ---------------- P = doc @ [W1_start | W1_end | W1_attn]  -> [NW][3072] ----------------
__global__ __launch_bounds__(256) void k_proj(const float* __restrict__ doc,
                                              const float* __restrict__ mlp1_w,
                                              float* __restrict__ P) {
    // grid: (3072/64, 4096/64)
    int col0 = blockIdx.x * 64;
    int row0 = blockIdx.y * 64;
    int part = col0 >> 10;
    int m0 = col0 & 1023;
    int rb = (part == 0) ? 0 : (part == 1 ? H : (2 * H + E));

    __shared__ float As[16][65];  // As[k][i], padded
    __shared__ float Bs[16][64];  // Bs[k][j]

    int tid = threadIdx.x;
    int tx = tid & 15, ty = tid >> 4;
    float acc[4][4] = {};

    for (int k0 = 0; k0 < H; k0 += 16) {
        {
            int i = tid >> 2, kq = (tid & 3) * 4;
            float4 a = *reinterpret_cast<const float4*>(doc + (size_t)(row0 + i) * H + k0 + kq);
            As[kq + 0][i] = a.x; As[kq + 1][i] = a.y; As[kq + 2][i] = a.z; As[kq + 3][i] = a.w;
        }
        {
            int k = tid >> 4, jq = (tid & 15) * 4;
            float4 b = *reinterpret_cast<const float4*>(mlp1_w + (size_t)(rb + k0 + k) * M + m0 + jq);
            *reinterpret_cast<float4*>(&Bs[k][jq]) = b;
        }
        __syncthreads();
        #pragma unroll
        for (int k = 0; k < 16; ++k) {
            float bv[4];
            *reinterpret_cast<float4*>(bv) = *reinterpret_cast<const float4*>(&Bs[k][tx * 4]);
            float av[4];
            #pragma unroll
            for (int r = 0; r < 4; ++r) av[r] = As[k][ty * 4 + r];
            #pragma unroll
            for (int r = 0; r < 4; ++r)
                #pragma unroll
                for (int c = 0; c < 4; ++c)
                    acc[r][c] = fmaf(av[r], bv[c], acc[r][c]);
        }
        __syncthreads();
    }
    #pragma unroll
    for (int r = 0; r < 4; ++r) {
        float4 o = make_float4(acc[r][0], acc[r][1], acc[r][2], acc[r][3]);
        *reinterpret_cast<float4*>(P + (size_t)(row0 + ty * 4 + r) * PCOLS + col0 + tx * 4) = o;
    }
}

// ---------------- per-candidate: h = relu(Pstart[s]+Pend[e]+PW[wi]+sum_i a_i*Pattn[i]); out = h.mlp2 + b + wscore ----------------
__global__ __launch_bounds__(256) void k_cand(const float* __restrict__ P,
                                              const float* __restrict__ PW,
                                              const float* __restrict__ word_attn,
                                              const float* __restrict__ wscore,
                                              const int* __restrict__ starts,
                                              const int* __restrict__ ends,
                                              const float* __restrict__ mlp2_w,
                                              const float* __restrict__ mlp2_b,
                                              float* __restrict__ out) {
    int c = blockIdx.x * 4 + (threadIdx.x >> 6);
    int lane = threadIdx.x & 63;
    int s = starts[c], e = ends[c];
    int wi = e - s;
    wi = wi < 0 ? 0 : (wi > MSW - 1 ? MSW - 1 : wi);
    int L = e - s + 1;

    // softmax over word_attn[s..e] (masked-out positions contribute exactly 0)
    float mx = -INFINITY;
    for (int i = 0; i < L; ++i) mx = fmaxf(mx, word_attn[s + i]);
    float denom = 0.f;
    for (int i = 0; i < L; ++i) denom += __expf(word_attn[s + i] - mx);
    float inv = 1.f / denom;

    const float* ps = P + (size_t)s * PCOLS;
    const float* pe = P + (size_t)e * PCOLS + 1024;
    const float* pw = PW + (size_t)wi * M;

    float4 acc[4];
    #pragma unroll
    for (int j = 0; j < 4; ++j) {
        int m = 4 * lane + 256 * j;
        float4 a = *reinterpret_cast<const float4*>(ps + m);
        float4 b = *reinterpret_cast<const float4*>(pe + m);
        float4 w = *reinterpret_cast<const float4*>(pw + m);
        acc[j].x = a.x + b.x + w.x;
        acc[j].y = a.y + b.y + w.y;
        acc[j].z = a.z + b.z + w.z;
        acc[j].w = a.w + b.w + w.w;
    }
    for (int i = 0; i < L; ++i) {
        float al = __expf(word_attn[s + i] - mx) * inv;
        const float* pa = P + (size_t)(s + i) * PCOLS + 2048;
        #pragma unroll
        for (int j = 0; j < 4; ++j) {
            int m = 4 * lane + 256 * j;
            float4 v = *reinterpret_cast<const float4*>(pa + m);
            acc[j].x = fmaf(al, v.x, acc[j].x);
            acc[j].y = fmaf(al, v.y, acc[j].y);
            acc[j].z = fmaf(al, v.z, acc[j].z);
            acc[j].w = fmaf(al, v.w, acc[j].w);
        }
    }
    float part = 0.f;
    #pragma unroll
    for (int j = 0; j < 4; ++j) {
        int m = 4 * lane + 256 * j;
        float4 w2 = *reinterpret_cast<const float4*>(mlp2_w + m);
        part += fmaxf(acc[j].x, 0.f) * w2.x + fmaxf(acc[j].y, 0.f) * w2.y +
                fmaxf(acc[j].z, 0.f) * w2.z + fmaxf(acc[j].w, 0.f) * w2.w;
    }
    #pragma unroll
    for (int off = 32; off > 0; off >>= 1) part += __shfl_down(part, off);
    if (lane == 0) out[c] = part + mlp2_b[0] + wscore[wi];
}

extern "C" void kernel_launch(void* const* d_in, const int* in_sizes, int n_in,
                              void* d_out, int out_size, void* d_ws, size_t ws_size,
                              hipStream_t stream) {
    const float* encoded_doc    = (const float*)d_in[0];
    const int*   cand_starts    = (const int*)d_in[1];
    const int*   cand_ends      = (const int*)d_in[2];
    const float* width_emb      = (const float*)d_in[3];
    const float* width_prior    = (const float*)d_in[4];
    const float* attn_w         = (const float*)d_in[5];
    const float* attn_b         = (const float*)d_in[6];
    const float* mlp1_w         = (const float*)d_in[7];
    const float* mlp1_b         = (const float*)d_in[8];
    const float* mlp2_w         = (const float*)d_in[9];
    const float* mlp2_b         = (const float*)d_in[10];
    const float* wmlp1_w        = (const float*)d_in[11];
    const float* wmlp1_b        = (const float*)d_in[12];
    const float* wmlp2_w        = (const float*)d_in[13];
    const float* wmlp2_b        = (const float*)d_in[14];
    float* out = (float*)d_out;

    // workspace layout (floats)
    float* P         = (float*)d_ws;                       // NW*3072
    float* word_attn = P + (size_t)NW * PCOLS;             // NW
    float* PW        = word_attn + NW;                     // 30*1024
    float* wscore    = PW + MSW * M;                       // 30

    k_word_attn<<<NW / 4, 256, 0, stream>>>(encoded_doc, attn_w, attn_b, word_attn);
    k_pw<<<dim3(MSW, M / 256), 256, 0, stream>>>(width_emb, mlp1_w, mlp1_b, PW);
    k_wscore<<<MSW, 256, 0, stream>>>(width_prior, wmlp1_w, wmlp1_b, wmlp2_w, wmlp2_b, wscore);
    k_proj<<<dim3(PCOLS / 64, NW / 64), 256, 0, stream>>>(encoded_doc, mlp1_w, P);
    k_cand<<<NC / 4, 256, 0, stream>>>(P, PW, word_attn, wscore,
                                       cand_starts, cand_ends, mlp2_w, mlp2_b, out);
}

// Round 2
// 388.893 us; speedup vs baseline: 1.6837x; 1.6837x over previous
//
#include <hip/hip_runtime.h>
#include <math.h>

#define NW 4096
#define H 768
#define NC 49152
#define MSW 30
#define E 20
#define M 1024
// P layout: [NW][3072]; cols 0:1024 start-proj, 1024:2048 end-proj,
// 2048:3072 attn-proj (later overwritten in place by exp-weighted prefix S,
// where P[r][2048+m] becomes S[r+1][m] = sum_{i<=r} ewa[i]*Pattn[i][m])
#define PCOLS 3072
#define CHUNK 64
#define NCH (NW / CHUNK)

// ---------------- ewa[row] = exp(doc[row] @ attn_w + attn_b) ----------------
__global__ __launch_bounds__(256) void k_ewa(const float* __restrict__ doc,
                                             const float* __restrict__ attn_w,
                                             const float* __restrict__ attn_b,
                                             float* __restrict__ ewa) {
    int row = blockIdx.x * 4 + (threadIdx.x >> 6);
    int lane = threadIdx.x & 63;
    const float* r = doc + (size_t)row * H;
    float s = 0.f;
    #pragma unroll
    for (int j = 0; j < H / 64; ++j) s += r[lane + 64 * j] * attn_w[lane + 64 * j];
    #pragma unroll
    for (int off = 32; off > 0; off >>= 1) s += __shfl_down(s, off);
    if (lane == 0) ewa[row] = expf(s + attn_b[0]);
}

// ---------------- Dpre[i] = sum_{j<i} ewa[j], i in [0, NW] ----------------
__global__ __launch_bounds__(256) void k_dscan(const float* __restrict__ ewa,
                                               float* __restrict__ Dpre) {
    int t = threadIdx.x;   // single block of 256, each thread owns 16 elems
    float v[16];
    float sum = 0.f;
    #pragma unroll
    for (int i = 0; i < 16; ++i) { v[i] = ewa[t * 16 + i]; sum += v[i]; }
    __shared__ float sh[256];
    sh[t] = sum;
    __syncthreads();
    for (int off = 1; off < 256; off <<= 1) {
        float x = (t >= off) ? sh[t - off] : 0.f;
        __syncthreads();
        sh[t] += x;
        __syncthreads();
    }
    float run = sh[t] - sum;   // exclusive prefix of this thread's chunk
    #pragma unroll
    for (int i = 0; i < 16; ++i) { run += v[i]; Dpre[t * 16 + i + 1] = run; }
    if (t == 0) Dpre[0] = 0.f;
}

// ---------------- PW[w][m] = width_emb[w] @ W1[2H:2H+E] + mlp1_b ----------------
__global__ __launch_bounds__(256) void k_pw(const float* __restrict__ width_emb,
                                            const float* __restrict__ mlp1_w,
                                            const float* __restrict__ mlp1_b,
                                            float* __restrict__ PW) {
    int w = blockIdx.x;
    int m = blockIdx.y * 256 + threadIdx.x;
    float acc = mlp1_b[m];
    #pragma unroll
    for (int e = 0; e < E; ++e)
        acc += width_emb[w * E + e] * mlp1_w[(size_t)(2 * H + e) * M + m];
    PW[w * M + m] = acc;
}

// ---------------- wscore[w] ----------------
__global__ __launch_bounds__(256) void k_wscore(const float* __restrict__ wp_emb,
                                                const float* __restrict__ w1,
                                                const float* __restrict__ b1,
                                                const float* __restrict__ w2,
                                                const float* __restrict__ b2,
                                                float* __restrict__ wscore) {
    int w = blockIdx.x;
    int tid = threadIdx.x;
    float part = 0.f;
    for (int m = tid; m < M; m += 256) {
        float h = b1[m];
        #pragma unroll
        for (int e = 0; e < E; ++e) h += wp_emb[w * E + e] * w1[e * M + m];
        part += fmaxf(h, 0.f) * w2[m];
    }
    __shared__ float red[256];
    red[tid] = part;
    __syncthreads();
    for (int s = 128; s > 0; s >>= 1) {
        if (tid < s) red[tid] += red[tid + s];
        __syncthreads();
    }
    if (tid == 0) wscore[w] = red[0] + b2[0];
}

// ---------------- P = doc @ [W1_start | W1_end | W1_attn]  -> [NW][3072] ----------------
__global__ __launch_bounds__(256) void k_proj(const float* __restrict__ doc,
                                              const float* __restrict__ mlp1_w,
                                              float* __restrict__ P) {
    int col0 = blockIdx.x * 64;
    int row0 = blockIdx.y * 64;
    int part = col0 >> 10;
    int m0 = col0 & 1023;
    int rb = (part == 0) ? 0 : (part == 1 ? H : (2 * H + E));

    __shared__ float As[16][65];
    __shared__ float Bs[16][64];

    int tid = threadIdx.x;
    int tx = tid & 15, ty = tid >> 4;
    float acc[4][4] = {};

    for (int k0 = 0; k0 < H; k0 += 16) {
        {
            int i = tid >> 2, kq = (tid & 3) * 4;
            float4 a = *reinterpret_cast<const float4*>(doc + (size_t)(row0 + i) * H + k0 + kq);
            As[kq + 0][i] = a.x; As[kq + 1][i] = a.y; As[kq + 2][i] = a.z; As[kq + 3][i] = a.w;
        }
        {
            int k = tid >> 4, jq = (tid & 15) * 4;
            float4 b = *reinterpret_cast<const float4*>(mlp1_w + (size_t)(rb + k0 + k) * M + m0 + jq);
            *reinterpret_cast<float4*>(&Bs[k][jq]) = b;
        }
        __syncthreads();
        #pragma unroll
        for (int k = 0; k < 16; ++k) {
            float bv[4];
            *reinterpret_cast<float4*>(bv) = *reinterpret_cast<const float4*>(&Bs[k][tx * 4]);
            float av[4];
            #pragma unroll
            for (int r = 0; r < 4; ++r) av[r] = As[k][ty * 4 + r];
            #pragma unroll
            for (int r = 0; r < 4; ++r)
                #pragma unroll
                for (int c = 0; c < 4; ++c)
                    acc[r][c] = fmaf(av[r], bv[c], acc[r][c]);
        }
        __syncthreads();
    }
    #pragma unroll
    for (int r = 0; r < 4; ++r) {
        float4 o = make_float4(acc[r][0], acc[r][1], acc[r][2], acc[r][3]);
        *reinterpret_cast<float4*>(P + (size_t)(row0 + ty * 4 + r) * PCOLS + col0 + tx * 4) = o;
    }
}

// ---------------- scan phase 1: per-chunk totals of ewa[i]*Pattn[i][m] ----------------
__global__ __launch_bounds__(256) void k_scan1(const float* __restrict__ P,
                                               const float* __restrict__ ewa,
                                               float* __restrict__ T) {
    int m = blockIdx.x * 256 + threadIdx.x;
    int c = blockIdx.y;
    __shared__ float ew[CHUNK];
    if (threadIdx.x < CHUNK) ew[threadIdx.x] = ewa[c * CHUNK + threadIdx.x];
    __syncthreads();
    const float* base = P + (size_t)(c * CHUNK) * PCOLS + 2048 + m;
    float acc = 0.f;
    #pragma unroll 8
    for (int i = 0; i < CHUNK; ++i)
        acc += ew[i] * base[(size_t)i * PCOLS];
    T[c * M + m] = acc;
}

// ---------------- scan phase 2: exclusive scan of chunk totals ----------------
__global__ __launch_bounds__(256) void k_scan2(float* __restrict__ T) {
    int m = blockIdx.x * 256 + threadIdx.x;
    float run = 0.f;
    for (int c = 0; c < NCH; ++c) {
        float t = T[c * M + m];
        T[c * M + m] = run;
        run += t;
    }
}

// ---------------- scan phase 3: in-place inclusive prefix into P's attn third ----------------
__global__ __launch_bounds__(256) void k_scan3(float* __restrict__ P,
                                               const float* __restrict__ ewa,
                                               const float* __restrict__ T) {
    int m = blockIdx.x * 256 + threadIdx.x;
    int c = blockIdx.y;
    __shared__ float ew[CHUNK];
    if (threadIdx.x < CHUNK) ew[threadIdx.x] = ewa[c * CHUNK + threadIdx.x];
    __syncthreads();
    float acc = T[c * M + m];
    float* base = P + (size_t)(c * CHUNK) * PCOLS + 2048 + m;
    #pragma unroll 4
    for (int i = 0; i < CHUNK; ++i) {
        float* p = base + (size_t)i * PCOLS;
        acc += ew[i] * (*p);
        *p = acc;   // Sstore[c*CHUNK+i][m] = S[c*CHUNK+i+1][m]
    }
}

// ---------------- per-candidate scoring ----------------
__global__ __launch_bounds__(256) void k_cand(const float* __restrict__ P,
                                              const float* __restrict__ PW,
                                              const float* __restrict__ Dpre,
                                              const float* __restrict__ wscore,
                                              const int* __restrict__ starts,
                                              const int* __restrict__ ends,
                                              const float* __restrict__ mlp2_w,
                                              const float* __restrict__ mlp2_b,
                                              float* __restrict__ out) {
    int c = blockIdx.x * 4 + (threadIdx.x >> 6);
    int lane = threadIdx.x & 63;
    int s = starts[c], e = ends[c];
    int wi = e - s;
    wi = wi < 0 ? 0 : (wi > MSW - 1 ? MSW - 1 : wi);

    float inv = 1.f / (Dpre[e + 1] - Dpre[s]);

    const float* ps = P + (size_t)s * PCOLS;              // start proj row
    const float* pe = P + (size_t)e * PCOLS + 1024;       // end proj row
    const float* se = P + (size_t)e * PCOLS + 2048;       // S[e+1]
    bool has_s = (s > 0);
    const float* ss = P + (size_t)(has_s ? s - 1 : 0) * PCOLS + 2048;  // S[s]
    const float* pw = PW + (size_t)wi * M;

    float part = 0.f;
    #pragma unroll
    for (int j = 0; j < 4; ++j) {
        int m = 4 * lane + 256 * j;
        float4 a = *reinterpret_cast<const float4*>(ps + m);
        float4 b = *reinterpret_cast<const float4*>(pe + m);
        float4 w = *reinterpret_cast<const float4*>(pw + m);
        float4 t = *reinterpret_cast<const float4*>(se + m);
        float4 u = has_s ? *reinterpret_cast<const float4*>(ss + m)
                         : make_float4(0.f, 0.f, 0.f, 0.f);
        float4 w2 = *reinterpret_cast<const float4*>(mlp2_w + m);
        float x0 = a.x + b.x + w.x + (t.x - u.x) * inv;
        float x1 = a.y + b.y + w.y + (t.y - u.y) * inv;
        float x2 = a.z + b.z + w.z + (t.z - u.z) * inv;
        float x3 = a.w + b.w + w.w + (t.w - u.w) * inv;
        part += fmaxf(x0, 0.f) * w2.x + fmaxf(x1, 0.f) * w2.y +
                fmaxf(x2, 0.f) * w2.z + fmaxf(x3, 0.f) * w2.w;
    }
    #pragma unroll
    for (int off = 32; off > 0; off >>= 1) part += __shfl_down(part, off);
    if (lane == 0) out[c] = part + mlp2_b[0] + wscore[wi];
}

extern "C" void kernel_launch(void* const* d_in, const int* in_sizes, int n_in,
                              void* d_out, int out_size, void* d_ws, size_t ws_size,
                              hipStream_t stream) {
    const float* encoded_doc = (const float*)d_in[0];
    const int*   cand_starts = (const int*)d_in[1];
    const int*   cand_ends   = (const int*)d_in[2];
    const float* width_emb   = (const float*)d_in[3];
    const float* width_prior = (const float*)d_in[4];
    const float* attn_w      = (const float*)d_in[5];
    const float* attn_b      = (const float*)d_in[6];
    const float* mlp1_w      = (const float*)d_in[7];
    const float* mlp1_b      = (const float*)d_in[8];
    const float* mlp2_w      = (const float*)d_in[9];
    const float* mlp2_b      = (const float*)d_in[10];
    const float* wmlp1_w     = (const float*)d_in[11];
    const float* wmlp1_b     = (const float*)d_in[12];
    const float* wmlp2_w     = (const float*)d_in[13];
    const float* wmlp2_b     = (const float*)d_in[14];
    float* out = (float*)d_out;

    // workspace layout (floats)
    float* P      = (float*)d_ws;                  // NW*3072
    float* ewa    = P + (size_t)NW * PCOLS;        // NW
    float* Dpre   = ewa + NW;                      // NW+1 (pad to 4160)
    float* PW     = Dpre + 4160;                   // 30*1024
    float* wscore = PW + MSW * M;                  // 30 (pad 64)
    float* T      = wscore + 64;                   // NCH*M = 64*1024

    k_ewa<<<NW / 4, 256, 0, stream>>>(encoded_doc, attn_w, attn_b, ewa);
    k_dscan<<<1, 256, 0, stream>>>(ewa, Dpre);
    k_pw<<<dim3(MSW, M / 256), 256, 0, stream>>>(width_emb, mlp1_w, mlp1_b, PW);
    k_wscore<<<MSW, 256, 0, stream>>>(width_prior, wmlp1_w, wmlp1_b, wmlp2_w, wmlp2_b, wscore);
    k_proj<<<dim3(PCOLS / 64, NW / 64), 256, 0, stream>>>(encoded_doc, mlp1_w, P);
    k_scan1<<<dim3(M / 256, NCH), 256, 0, stream>>>(P, ewa, T);
    k_scan2<<<M / 256, 256, 0, stream>>>(T);
    k_scan3<<<dim3(M / 256, NCH), 256, 0, stream>>>(P, ewa, T);
    k_cand<<<NC / 4, 256, 0, stream>>>(P, PW, Dpre, wscore,
                                       cand_starts, cand_ends, mlp2_w, mlp2_b, out);
}

// Round 3
// 189.288 us; speedup vs baseline: 3.4592x; 2.0545x over previous
//
#include <hip/hip_runtime.h>
#include <math.h>

#define NW 4096
#define H 768
#define NC 49152
#define MSW 30
#define E 20
#define M 1024
// P layout: [NW][3072]; cols 0:1024 start-proj, 1024:2048 end-proj,
// 2048:3072 attn-proj (later overwritten in place by exp-weighted prefix S,
// where P[r][2048+m] = S[r+1][m] = sum_{i<=r} ewa[i]*Pattn[i][m])
#define PCOLS 3072
#define CHUNK 64
#define NCH (NW / CHUNK)

typedef short bf16x8 __attribute__((ext_vector_type(8)));
typedef float f32x4 __attribute__((ext_vector_type(4)));

__device__ __forceinline__ unsigned short f2bf(float x) {
    unsigned u = __float_as_uint(x);
    unsigned r = (u + 0x7fff + ((u >> 16) & 1)) >> 16;  // RNE
    return (unsigned short)r;
}

__device__ __forceinline__ void gload16(const void* g, void* l) {
    __builtin_amdgcn_global_load_lds((const __attribute__((address_space(1))) void*)g,
                                     (__attribute__((address_space(3))) void*)l, 16, 0, 0);
}

// ---------------- docb = bf16(doc) ----------------
__global__ __launch_bounds__(256) void k_cvt_doc(const float* __restrict__ doc,
                                                 unsigned short* __restrict__ docb) {
    int i = (blockIdx.x * 256 + threadIdx.x) * 4;
    float4 v = *reinterpret_cast<const float4*>(doc + i);
    ushort4 o;
    o.x = f2bf(v.x); o.y = f2bf(v.y); o.z = f2bf(v.z); o.w = f2bf(v.w);
    *reinterpret_cast<ushort4*>(docb + i) = o;
}

// ---------------- Bt[col][k] = bf16(mlp1_w[rb(part)+k][m]), col = part*1024+m ----------------
__global__ __launch_bounds__(256) void k_cvt_bt(const float* __restrict__ mlp1_w,
                                                unsigned short* __restrict__ Bt) {
    __shared__ float sh[32][33];
    int k0 = blockIdx.x * 32, m0 = blockIdx.y * 32, part = blockIdx.z;
    int rb = part == 0 ? 0 : (part == 1 ? H : (2 * H + E));
    int tx = threadIdx.x & 31, ty = threadIdx.x >> 5;
    #pragma unroll
    for (int it = 0; it < 4; ++it) {
        int kk = ty + it * 8;
        sh[kk][tx] = mlp1_w[(size_t)(rb + k0 + kk) * M + m0 + tx];
    }
    __syncthreads();
    #pragma unroll
    for (int it = 0; it < 4; ++it) {
        int mm = ty + it * 8;
        Bt[(size_t)(part * M + m0 + mm) * H + k0 + tx] = f2bf(sh[tx][mm]);
    }
}

// ---------------- ewa[row] = exp(doc[row] @ attn_w + attn_b) ----------------
__global__ __launch_bounds__(256) void k_ewa(const float* __restrict__ doc,
                                             const float* __restrict__ attn_w,
                                             const float* __restrict__ attn_b,
                                             float* __restrict__ ewa) {
    int row = blockIdx.x * 4 + (threadIdx.x >> 6);
    int lane = threadIdx.x & 63;
    const float* r = doc + (size_t)row * H;
    float s = 0.f;
    #pragma unroll
    for (int j = 0; j < H / 64; ++j) s += r[lane + 64 * j] * attn_w[lane + 64 * j];
    #pragma unroll
    for (int off = 32; off > 0; off >>= 1) s += __shfl_down(s, off);
    if (lane == 0) ewa[row] = expf(s + attn_b[0]);
}

// ---------------- Dpre[i] = sum_{j<i} ewa[j] ----------------
__global__ __launch_bounds__(256) void k_dscan(const float* __restrict__ ewa,
                                               float* __restrict__ Dpre) {
    int t = threadIdx.x;
    float v[16];
    float sum = 0.f;
    #pragma unroll
    for (int i = 0; i < 16; ++i) { v[i] = ewa[t * 16 + i]; sum += v[i]; }
    __shared__ float sh[256];
    sh[t] = sum;
    __syncthreads();
    for (int off = 1; off < 256; off <<= 1) {
        float x = (t >= off) ? sh[t - off] : 0.f;
        __syncthreads();
        sh[t] += x;
        __syncthreads();
    }
    float run = sh[t] - sum;
    #pragma unroll
    for (int i = 0; i < 16; ++i) { run += v[i]; Dpre[t * 16 + i + 1] = run; }
    if (t == 0) Dpre[0] = 0.f;
}

// ---------------- PW[w][m] = width_emb[w] @ W1[2H:2H+E] + mlp1_b ----------------
__global__ __launch_bounds__(256) void k_pw(const float* __restrict__ width_emb,
                                            const float* __restrict__ mlp1_w,
                                            const float* __restrict__ mlp1_b,
                                            float* __restrict__ PW) {
    int w = blockIdx.x;
    int m = blockIdx.y * 256 + threadIdx.x;
    float acc = mlp1_b[m];
    #pragma unroll
    for (int e = 0; e < E; ++e)
        acc += width_emb[w * E + e] * mlp1_w[(size_t)(2 * H + e) * M + m];
    PW[w * M + m] = acc;
}

// ---------------- wscore[w] ----------------
__global__ __launch_bounds__(256) void k_wscore(const float* __restrict__ wp_emb,
                                                const float* __restrict__ w1,
                                                const float* __restrict__ b1,
                                                const float* __restrict__ w2,
                                                const float* __restrict__ b2,
                                                float* __restrict__ wscore) {
    int w = blockIdx.x;
    int tid = threadIdx.x;
    float part = 0.f;
    for (int m = tid; m < M; m += 256) {
        float h = b1[m];
        #pragma unroll
        for (int e = 0; e < E; ++e) h += wp_emb[w * E + e] * w1[e * M + m];
        part += fmaxf(h, 0.f) * w2[m];
    }
    __shared__ float red[256];
    red[tid] = part;
    __syncthreads();
    for (int s = 128; s > 0; s >>= 1) {
        if (tid < s) red[tid] += red[tid + s];
        __syncthreads();
    }
    if (tid == 0) wscore[w] = red[0] + b2[0];
}

// ---------------- MFMA projection: P = docb @ Bt^T -> [NW][3072] fp32 ----------------
// A tile 128x64 bf16, B tile 64x128 bf16, fragment-ordered LDS (all ds_reads linear).
__global__ __launch_bounds__(256) void k_proj_mfma(const unsigned short* __restrict__ docb,
                                                   const unsigned short* __restrict__ Bt,
                                                   float* __restrict__ P) {
    __shared__ unsigned short As[8192];  // [R16:8][ks:2][g:4][ri:16][j:8]
    __shared__ unsigned short Bs[8192];  // [C16:8][ks:2][g:4][ci:16][j:8]
    int tid = threadIdx.x;
    int col0 = blockIdx.x * 128;
    int row0 = blockIdx.y * 128;
    int wv = tid >> 6, lane = tid & 63;
    int wr = wv >> 1, wc = wv & 1;

    f32x4 acc[4][4];
    #pragma unroll
    for (int mi = 0; mi < 4; ++mi)
        #pragma unroll
        for (int ni = 0; ni < 4; ++ni) acc[mi][ni] = (f32x4){0.f, 0.f, 0.f, 0.f};

    for (int k0 = 0; k0 < H; k0 += 64) {
        __syncthreads();
        #pragma unroll
        for (int i = 0; i < 4; ++i) {
            int s = i * 256 + tid;
            int rr = s >> 7;          // group-of-16 (rows for A, cols for B)
            int ks = (s >> 6) & 1;
            int g  = (s >> 4) & 3;
            int ri = s & 15;
            int kloc = k0 + ks * 32 + g * 8;
            gload16(docb + (size_t)(row0 + rr * 16 + ri) * H + kloc, (char*)As + s * 16);
            gload16(Bt   + (size_t)(col0 + rr * 16 + ri) * H + kloc, (char*)Bs + s * 16);
        }
        __syncthreads();  // drains vmcnt before any wave reads LDS
        #pragma unroll
        for (int ks = 0; ks < 2; ++ks) {
            bf16x8 af[4], bfr[4];
            #pragma unroll
            for (int mi = 0; mi < 4; ++mi)
                af[mi] = *reinterpret_cast<const bf16x8*>(
                    (char*)As + (wr * 4 + mi) * 2048 + ks * 1024 + lane * 16);
            #pragma unroll
            for (int ni = 0; ni < 4; ++ni)
                bfr[ni] = *reinterpret_cast<const bf16x8*>(
                    (char*)Bs + (wc * 4 + ni) * 2048 + ks * 1024 + lane * 16);
            #pragma unroll
            for (int mi = 0; mi < 4; ++mi)
                #pragma unroll
                for (int ni = 0; ni < 4; ++ni)
                    acc[mi][ni] = __builtin_amdgcn_mfma_f32_16x16x32_bf16(
                        af[mi], bfr[ni], acc[mi][ni], 0, 0, 0);
        }
    }
    int cr = (lane >> 4) * 4;
    int cc = lane & 15;
    #pragma unroll
    for (int mi = 0; mi < 4; ++mi) {
        #pragma unroll
        for (int ni = 0; ni < 4; ++ni) {
            int r = row0 + wr * 64 + mi * 16 + cr;
            int c = col0 + wc * 64 + ni * 16 + cc;
            float* dst = P + (size_t)r * PCOLS + c;
            #pragma unroll
            for (int j = 0; j < 4; ++j) dst[(size_t)j * PCOLS] = acc[mi][ni][j];
        }
    }
}

// ---------------- scan phase 1: per-chunk totals of ewa[i]*Pattn[i][m] ----------------
__global__ __launch_bounds__(256) void k_scan1(const float* __restrict__ P,
                                               const float* __restrict__ ewa,
                                               float* __restrict__ T) {
    int m = blockIdx.x * 256 + threadIdx.x;
    int c = blockIdx.y;
    __shared__ float ew[CHUNK];
    if (threadIdx.x < CHUNK) ew[threadIdx.x] = ewa[c * CHUNK + threadIdx.x];
    __syncthreads();
    const float* base = P + (size_t)(c * CHUNK) * PCOLS + 2048 + m;
    float acc = 0.f;
    #pragma unroll 8
    for (int i = 0; i < CHUNK; ++i)
        acc += ew[i] * base[(size_t)i * PCOLS];
    T[c * M + m] = acc;
}

// ---------------- scan phase 2: exclusive scan of chunk totals (reg-resident) ----------------
__global__ __launch_bounds__(256) void k_scan2(float* __restrict__ T) {
    int m = blockIdx.x * 256 + threadIdx.x;
    float v[NCH];
    #pragma unroll
    for (int c = 0; c < NCH; ++c) v[c] = T[c * M + m];
    float run = 0.f;
    #pragma unroll
    for (int c = 0; c < NCH; ++c) { float t = v[c]; T[c * M + m] = run; run += t; }
}

// ---------------- scan phase 3: in-place inclusive prefix into P's attn third ----------------
__global__ __launch_bounds__(256) void k_scan3(float* __restrict__ P,
                                               const float* __restrict__ ewa,
                                               const float* __restrict__ T) {
    int m = blockIdx.x * 256 + threadIdx.x;
    int c = blockIdx.y;
    __shared__ float ew[CHUNK];
    if (threadIdx.x < CHUNK) ew[threadIdx.x] = ewa[c * CHUNK + threadIdx.x];
    __syncthreads();
    float acc = T[c * M + m];
    float* base = P + (size_t)(c * CHUNK) * PCOLS + 2048 + m;
    #pragma unroll 4
    for (int i = 0; i < CHUNK; ++i) {
        float* p = base + (size_t)i * PCOLS;
        acc += ew[i] * (*p);
        *p = acc;
    }
}

// ---------------- per-candidate scoring ----------------
__global__ __launch_bounds__(256) void k_cand(const float* __restrict__ P,
                                              const float* __restrict__ PW,
                                              const float* __restrict__ Dpre,
                                              const float* __restrict__ wscore,
                                              const int* __restrict__ starts,
                                              const int* __restrict__ ends,
                                              const float* __restrict__ mlp2_w,
                                              const float* __restrict__ mlp2_b,
                                              float* __restrict__ out) {
    int c = blockIdx.x * 4 + (threadIdx.x >> 6);
    int lane = threadIdx.x & 63;
    int s = starts[c], e = ends[c];
    int wi = e - s;
    wi = wi < 0 ? 0 : (wi > MSW - 1 ? MSW - 1 : wi);

    float inv = 1.f / (Dpre[e + 1] - Dpre[s]);

    const float* ps = P + (size_t)s * PCOLS;
    const float* pe = P + (size_t)e * PCOLS + 1024;
    const float* se = P + (size_t)e * PCOLS + 2048;
    bool has_s = (s > 0);
    const float* ss = P + (size_t)(has_s ? s - 1 : 0) * PCOLS + 2048;
    const float* pw = PW + (size_t)wi * M;

    float part = 0.f;
    #pragma unroll
    for (int j = 0; j < 4; ++j) {
        int m = 4 * lane + 256 * j;
        float4 a = *reinterpret_cast<const float4*>(ps + m);
        float4 b = *reinterpret_cast<const float4*>(pe + m);
        float4 w = *reinterpret_cast<const float4*>(pw + m);
        float4 t = *reinterpret_cast<const float4*>(se + m);
        float4 u = has_s ? *reinterpret_cast<const float4*>(ss + m)
                         : make_float4(0.f, 0.f, 0.f, 0.f);
        float4 w2 = *reinterpret_cast<const float4*>(mlp2_w + m);
        float x0 = a.x + b.x + w.x + (t.x - u.x) * inv;
        float x1 = a.y + b.y + w.y + (t.y - u.y) * inv;
        float x2 = a.z + b.z + w.z + (t.z - u.z) * inv;
        float x3 = a.w + b.w + w.w + (t.w - u.w) * inv;
        part += fmaxf(x0, 0.f) * w2.x + fmaxf(x1, 0.f) * w2.y +
                fmaxf(x2, 0.f) * w2.z + fmaxf(x3, 0.f) * w2.w;
    }
    #pragma unroll
    for (int off = 32; off > 0; off >>= 1) part += __shfl_down(part, off);
    if (lane == 0) out[c] = part + mlp2_b[0] + wscore[wi];
}

extern "C" void kernel_launch(void* const* d_in, const int* in_sizes, int n_in,
                              void* d_out, int out_size, void* d_ws, size_t ws_size,
                              hipStream_t stream) {
    const float* encoded_doc = (const float*)d_in[0];
    const int*   cand_starts = (const int*)d_in[1];
    const int*   cand_ends   = (const int*)d_in[2];
    const float* width_emb   = (const float*)d_in[3];
    const float* width_prior = (const float*)d_in[4];
    const float* attn_w      = (const float*)d_in[5];
    const float* attn_b      = (const float*)d_in[6];
    const float* mlp1_w      = (const float*)d_in[7];
    const float* mlp1_b      = (const float*)d_in[8];
    const float* mlp2_w      = (const float*)d_in[9];
    const float* mlp2_b      = (const float*)d_in[10];
    const float* wmlp1_w     = (const float*)d_in[11];
    const float* wmlp1_b     = (const float*)d_in[12];
    const float* wmlp2_w     = (const float*)d_in[13];
    const float* wmlp2_b     = (const float*)d_in[14];
    float* out = (float*)d_out;

    // workspace layout (float units)
    float* P      = (float*)d_ws;                  // NW*3072
    float* ewa    = P + (size_t)NW * PCOLS;        // NW
    float* Dpre   = ewa + NW;                      // NW+1 (pad 4160)
    float* PW     = Dpre + 4160;                   // 30*1024
    float* wscore = PW + MSW * M;                  // 30 (pad 64)
    float* T      = wscore + 64;                   // NCH*M
    unsigned short* docb = (unsigned short*)(T + NCH * M);      // NW*H bf16
    unsigned short* Btb  = docb + (size_t)NW * H;               // 3072*H bf16

    k_cvt_doc<<<(NW * H) / 1024, 256, 0, stream>>>(encoded_doc, docb);
    k_cvt_bt<<<dim3(H / 32, M / 32, 3), 256, 0, stream>>>(mlp1_w, Btb);
    k_ewa<<<NW / 4, 256, 0, stream>>>(encoded_doc, attn_w, attn_b, ewa);
    k_dscan<<<1, 256, 0, stream>>>(ewa, Dpre);
    k_pw<<<dim3(MSW, M / 256), 256, 0, stream>>>(width_emb, mlp1_w, mlp1_b, PW);
    k_wscore<<<MSW, 256, 0, stream>>>(width_prior, wmlp1_w, wmlp1_b, wmlp2_w, wmlp2_b, wscore);
    k_proj_mfma<<<dim3(PCOLS / 128, NW / 128), 256, 0, stream>>>(docb, Btb, P);
    k_scan1<<<dim3(M / 256, NCH), 256, 0, stream>>>(P, ewa, T);
    k_scan2<<<M / 256, 256, 0, stream>>>(T);
    k_scan3<<<dim3(M / 256, NCH), 256, 0, stream>>>(P, ewa, T);
    k_cand<<<NC / 4, 256, 0, stream>>>(P, PW, Dpre, wscore,
                                       cand_starts, cand_ends, mlp2_w, mlp2_b, out);
}

// Round 4
// 139.851 us; speedup vs baseline: 4.6820x; 1.3535x over previous
//
#include <hip/hip_runtime.h>
#include <math.h>

#define NW 4096
#define H 768
#define NC 49152
#define MSW 30
#define E 20
#define M 1024
#define CHUNK 64
#define NCH (NW / CHUNK)
// Pse: bf16 [NW][2048] (cols 0:1024 start-proj, 1024:2048 end-proj)
// Sbuf: f32 [NW][1024] attn-proj, overwritten in place by exp-weighted prefix:
//   Sbuf[r][m] = S[r+1][m] = sum_{i<=r} ewa[i]*Pattn[i][m]

typedef short bf16x8 __attribute__((ext_vector_type(8)));
typedef unsigned short u16x8 __attribute__((ext_vector_type(8)));
typedef float f32x4 __attribute__((ext_vector_type(4)));

__device__ __forceinline__ unsigned short f2bf(float x) {
    unsigned u = __float_as_uint(x);
    return (unsigned short)((u + 0x7fff + ((u >> 16) & 1)) >> 16);  // RNE
}
__device__ __forceinline__ float bf2f(unsigned short b) {
    return __uint_as_float(((unsigned)b) << 16);
}
__device__ __forceinline__ void gload16(const void* g, void* l) {
    __builtin_amdgcn_global_load_lds((const __attribute__((address_space(1))) void*)g,
                                     (__attribute__((address_space(3))) void*)l, 16, 0, 0);
}

// ---------------- fused: docb = bf16(doc); ewa = exp(doc @ attn_w + b) ----------------
__global__ __launch_bounds__(256) void k_doc_prep(const float* __restrict__ doc,
                                                  const float* __restrict__ attn_w,
                                                  const float* __restrict__ attn_b,
                                                  unsigned short* __restrict__ docb,
                                                  float* __restrict__ ewa) {
    int row = blockIdx.x * 4 + (threadIdx.x >> 6);
    int lane = threadIdx.x & 63;
    const float* r = doc + (size_t)row * H;
    float s = 0.f;
    #pragma unroll
    for (int q = 0; q < 3; ++q) {
        int idx = q * 256 + lane * 4;
        float4 v = *reinterpret_cast<const float4*>(r + idx);
        float4 w = *reinterpret_cast<const float4*>(attn_w + idx);
        s += v.x * w.x + v.y * w.y + v.z * w.z + v.w * w.w;
        ushort4 o;
        o.x = f2bf(v.x); o.y = f2bf(v.y); o.z = f2bf(v.z); o.w = f2bf(v.w);
        *reinterpret_cast<ushort4*>(docb + (size_t)row * H + idx) = o;
    }
    #pragma unroll
    for (int off = 32; off > 0; off >>= 1) s += __shfl_down(s, off);
    if (lane == 0) ewa[row] = expf(s + attn_b[0]);
}

// ---------------- Bt[col][k] = bf16(mlp1_w[rb(part)+k][m]), col = part*1024+m ----------------
__global__ __launch_bounds__(256) void k_cvt_bt(const float* __restrict__ mlp1_w,
                                                unsigned short* __restrict__ Bt) {
    __shared__ float sh[32][33];
    int k0 = blockIdx.x * 32, m0 = blockIdx.y * 32, part = blockIdx.z;
    int rb = part == 0 ? 0 : (part == 1 ? H : (2 * H + E));
    int tx = threadIdx.x & 31, ty = threadIdx.x >> 5;
    #pragma unroll
    for (int it = 0; it < 4; ++it) {
        int kk = ty + it * 8;
        sh[kk][tx] = mlp1_w[(size_t)(rb + k0 + kk) * M + m0 + tx];
    }
    __syncthreads();
    #pragma unroll
    for (int it = 0; it < 4; ++it) {
        int mm = ty + it * 8;
        Bt[(size_t)(part * M + m0 + mm) * H + k0 + tx] = f2bf(sh[tx][mm]);
    }
}

// ---------------- Dpre[i] = sum_{j<i} ewa[j] ----------------
__global__ __launch_bounds__(256) void k_dscan(const float* __restrict__ ewa,
                                               float* __restrict__ Dpre) {
    int t = threadIdx.x;
    float v[16];
    float sum = 0.f;
    #pragma unroll
    for (int i = 0; i < 16; ++i) { v[i] = ewa[t * 16 + i]; sum += v[i]; }
    __shared__ float sh[256];
    sh[t] = sum;
    __syncthreads();
    for (int off = 1; off < 256; off <<= 1) {
        float x = (t >= off) ? sh[t - off] : 0.f;
        __syncthreads();
        sh[t] += x;
        __syncthreads();
    }
    float run = sh[t] - sum;
    #pragma unroll
    for (int i = 0; i < 16; ++i) { run += v[i]; Dpre[t * 16 + i + 1] = run; }
    if (t == 0) Dpre[0] = 0.f;
}

// ---------------- PW[w][m] = width_emb[w] @ W1[2H:2H+E] + mlp1_b ----------------
__global__ __launch_bounds__(256) void k_pw(const float* __restrict__ width_emb,
                                            const float* __restrict__ mlp1_w,
                                            const float* __restrict__ mlp1_b,
                                            float* __restrict__ PW) {
    int w = blockIdx.x;
    int m = blockIdx.y * 256 + threadIdx.x;
    float acc = mlp1_b[m];
    #pragma unroll
    for (int e = 0; e < E; ++e)
        acc += width_emb[w * E + e] * mlp1_w[(size_t)(2 * H + e) * M + m];
    PW[w * M + m] = acc;
}

// ---------------- wscore[w] ----------------
__global__ __launch_bounds__(256) void k_wscore(const float* __restrict__ wp_emb,
                                                const float* __restrict__ w1,
                                                const float* __restrict__ b1,
                                                const float* __restrict__ w2,
                                                const float* __restrict__ b2,
                                                float* __restrict__ wscore) {
    int w = blockIdx.x;
    int tid = threadIdx.x;
    float part = 0.f;
    for (int m = tid; m < M; m += 256) {
        float h = b1[m];
        #pragma unroll
        for (int e = 0; e < E; ++e) h += wp_emb[w * E + e] * w1[e * M + m];
        part += fmaxf(h, 0.f) * w2[m];
    }
    __shared__ float red[256];
    red[tid] = part;
    __syncthreads();
    for (int s = 128; s > 0; s >>= 1) {
        if (tid < s) red[tid] += red[tid + s];
        __syncthreads();
    }
    if (tid == 0) wscore[w] = red[0] + b2[0];
}

// ---------------- sort-by-start: zero / hist / exclusive-scan / scatter ----------------
__global__ __launch_bounds__(256) void k_zero(int* __restrict__ hist) {
    hist[blockIdx.x * 256 + threadIdx.x] = 0;
}
__global__ __launch_bounds__(256) void k_hist(const int* __restrict__ starts,
                                              int* __restrict__ hist) {
    atomicAdd(&hist[starts[blockIdx.x * 256 + threadIdx.x]], 1);
}
__global__ __launch_bounds__(256) void k_hscan(const int* __restrict__ hist,
                                               int* __restrict__ offs) {
    int t = threadIdx.x;
    int v[16];
    int sum = 0;
    #pragma unroll
    for (int i = 0; i < 16; ++i) { v[i] = hist[t * 16 + i]; sum += v[i]; }
    __shared__ int sh[256];
    sh[t] = sum;
    __syncthreads();
    for (int off = 1; off < 256; off <<= 1) {
        int x = (t >= off) ? sh[t - off] : 0;
        __syncthreads();
        sh[t] += x;
        __syncthreads();
    }
    int run = sh[t] - sum;
    #pragma unroll
    for (int i = 0; i < 16; ++i) { offs[t * 16 + i] = run; run += v[i]; }
}
__global__ __launch_bounds__(256) void k_scatter(const int* __restrict__ starts,
                                                 int* __restrict__ offs,
                                                 int* __restrict__ perm) {
    int c = blockIdx.x * 256 + threadIdx.x;
    int p = atomicAdd(&offs[starts[c]], 1);
    perm[p] = c;
}

// ---------------- MFMA projection: bf16 Pse (parts 0,1) + f32 Sbuf (part 2) ----------------
__global__ __launch_bounds__(256) void k_proj_mfma(const unsigned short* __restrict__ docb,
                                                   const unsigned short* __restrict__ Bt,
                                                   unsigned short* __restrict__ Pse,
                                                   float* __restrict__ Sbuf) {
    __shared__ unsigned short As[8192];  // [R16:8][ks:2][g:4][ri:16][j:8]
    __shared__ unsigned short Bs[8192];
    int tid = threadIdx.x;
    int col0 = blockIdx.x * 128;
    int row0 = blockIdx.y * 128;
    int part = col0 >> 10;
    int cbase = col0 & 1023;
    int wv = tid >> 6, lane = tid & 63;
    int wr = wv >> 1, wc = wv & 1;

    f32x4 acc[4][4];
    #pragma unroll
    for (int mi = 0; mi < 4; ++mi)
        #pragma unroll
        for (int ni = 0; ni < 4; ++ni) acc[mi][ni] = (f32x4){0.f, 0.f, 0.f, 0.f};

    for (int k0 = 0; k0 < H; k0 += 64) {
        __syncthreads();
        #pragma unroll
        for (int i = 0; i < 4; ++i) {
            int s = i * 256 + tid;
            int rr = s >> 7;
            int ks = (s >> 6) & 1;
            int g  = (s >> 4) & 3;
            int ri = s & 15;
            int kloc = k0 + ks * 32 + g * 8;
            gload16(docb + (size_t)(row0 + rr * 16 + ri) * H + kloc, (char*)As + s * 16);
            gload16(Bt   + (size_t)(col0 + rr * 16 + ri) * H + kloc, (char*)Bs + s * 16);
        }
        __syncthreads();
        #pragma unroll
        for (int ks = 0; ks < 2; ++ks) {
            bf16x8 af[4], bfr[4];
            #pragma unroll
            for (int mi = 0; mi < 4; ++mi)
                af[mi] = *reinterpret_cast<const bf16x8*>(
                    (char*)As + (wr * 4 + mi) * 2048 + ks * 1024 + lane * 16);
            #pragma unroll
            for (int ni = 0; ni < 4; ++ni)
                bfr[ni] = *reinterpret_cast<const bf16x8*>(
                    (char*)Bs + (wc * 4 + ni) * 2048 + ks * 1024 + lane * 16);
            #pragma unroll
            for (int mi = 0; mi < 4; ++mi)
                #pragma unroll
                for (int ni = 0; ni < 4; ++ni)
                    acc[mi][ni] = __builtin_amdgcn_mfma_f32_16x16x32_bf16(
                        af[mi], bfr[ni], acc[mi][ni], 0, 0, 0);
        }
    }
    int cr = (lane >> 4) * 4;
    int cc = lane & 15;
    #pragma unroll
    for (int mi = 0; mi < 4; ++mi) {
        #pragma unroll
        for (int ni = 0; ni < 4; ++ni) {
            int r = row0 + wr * 64 + mi * 16 + cr;
            int c = cbase + wc * 64 + ni * 16 + cc;
            if (part < 2) {
                unsigned short* dst = Pse + (size_t)r * 2048 + part * 1024 + c;
                #pragma unroll
                for (int j = 0; j < 4; ++j) dst[(size_t)j * 2048] = f2bf(acc[mi][ni][j]);
            } else {
                float* dst = Sbuf + (size_t)r * M + c;
                #pragma unroll
                for (int j = 0; j < 4; ++j) dst[(size_t)j * M] = acc[mi][ni][j];
            }
        }
    }
}

// ---------------- scan phase 1: per-chunk totals of ewa[i]*Pattn[i][m] ----------------
__global__ __launch_bounds__(256) void k_scan1(const float* __restrict__ Sbuf,
                                               const float* __restrict__ ewa,
                                               float* __restrict__ T) {
    int m = blockIdx.x * 256 + threadIdx.x;
    int c = blockIdx.y;
    __shared__ float ew[CHUNK];
    if (threadIdx.x < CHUNK) ew[threadIdx.x] = ewa[c * CHUNK + threadIdx.x];
    __syncthreads();
    const float* base = Sbuf + (size_t)(c * CHUNK) * M + m;
    float acc = 0.f;
    #pragma unroll 8
    for (int i = 0; i < CHUNK; ++i)
        acc += ew[i] * base[(size_t)i * M];
    T[c * M + m] = acc;
}

// ---------------- scan phase 2: exclusive scan of chunk totals (reg-resident) ----------------
__global__ __launch_bounds__(256) void k_scan2(float* __restrict__ T) {
    int m = blockIdx.x * 256 + threadIdx.x;
    float v[NCH];
    #pragma unroll
    for (int c = 0; c < NCH; ++c) v[c] = T[c * M + m];
    float run = 0.f;
    #pragma unroll
    for (int c = 0; c < NCH; ++c) { float t = v[c]; T[c * M + m] = run; run += t; }
}

// ---------------- scan phase 3: in-place inclusive prefix over Sbuf ----------------
__global__ __launch_bounds__(256) void k_scan3(float* __restrict__ Sbuf,
                                               const float* __restrict__ ewa,
                                               const float* __restrict__ T) {
    int m = blockIdx.x * 256 + threadIdx.x;
    int c = blockIdx.y;
    __shared__ float ew[CHUNK];
    if (threadIdx.x < CHUNK) ew[threadIdx.x] = ewa[c * CHUNK + threadIdx.x];
    __syncthreads();
    float acc = T[c * M + m];
    float* base = Sbuf + (size_t)(c * CHUNK) * M + m;
    #pragma unroll 4
    for (int i = 0; i < CHUNK; ++i) {
        float* p = base + (size_t)i * M;
        acc += ew[i] * (*p);
        *p = acc;
    }
}

// ---------------- per-candidate scoring (sorted order, XCD-swizzled) ----------------
__global__ __launch_bounds__(256) void k_cand(const unsigned short* __restrict__ Pse,
                                              const float* __restrict__ Sbuf,
                                              const float* __restrict__ PW,
                                              const float* __restrict__ Dpre,
                                              const float* __restrict__ wscore,
                                              const int* __restrict__ perm,
                                              const int* __restrict__ starts,
                                              const int* __restrict__ ends,
                                              const float* __restrict__ mlp2_w,
                                              const float* __restrict__ mlp2_b,
                                              float* __restrict__ out) {
    int bid = blockIdx.x;                                   // 12288 blocks, %8==0 -> bijective
    int eff = (bid & 7) * (12288 / 8) + (bid >> 3);         // XCD-contiguous sorted ranges
    int j = eff * 4 + (threadIdx.x >> 6);
    int lane = threadIdx.x & 63;
    int c = perm[j];
    int s = starts[c], e = ends[c];
    int wi = e - s;
    wi = wi < 0 ? 0 : (wi > MSW - 1 ? MSW - 1 : wi);

    float inv = 1.f / (Dpre[e + 1] - Dpre[s]);

    const unsigned short* ps = Pse + (size_t)s * 2048;
    const unsigned short* pe = Pse + (size_t)e * 2048 + 1024;
    const float* se = Sbuf + (size_t)e * M;                 // S[e+1]
    const float* ss = Sbuf + (size_t)(s > 0 ? s - 1 : 0) * M;  // S[s]
    const float* pw = PW + (size_t)wi * M;
    bool has_s = (s > 0);

    float part = 0.f;
    #pragma unroll
    for (int q = 0; q < 2; ++q) {
        int m = lane * 8 + q * 512;
        u16x8 a8 = *reinterpret_cast<const u16x8*>(ps + m);
        u16x8 b8 = *reinterpret_cast<const u16x8*>(pe + m);
        float4 t0 = *reinterpret_cast<const float4*>(se + m);
        float4 t1 = *reinterpret_cast<const float4*>(se + m + 4);
        float4 u0 = make_float4(0.f, 0.f, 0.f, 0.f), u1 = u0;
        if (has_s) {
            u0 = *reinterpret_cast<const float4*>(ss + m);
            u1 = *reinterpret_cast<const float4*>(ss + m + 4);
        }
        float4 w0 = *reinterpret_cast<const float4*>(pw + m);
        float4 w1 = *reinterpret_cast<const float4*>(pw + m + 4);
        float4 v0 = *reinterpret_cast<const float4*>(mlp2_w + m);
        float4 v1 = *reinterpret_cast<const float4*>(mlp2_w + m + 4);
        float x;
        x = bf2f(a8[0]) + bf2f(b8[0]) + w0.x + (t0.x - u0.x) * inv; part += fmaxf(x, 0.f) * v0.x;
        x = bf2f(a8[1]) + bf2f(b8[1]) + w0.y + (t0.y - u0.y) * inv; part += fmaxf(x, 0.f) * v0.y;
        x = bf2f(a8[2]) + bf2f(b8[2]) + w0.z + (t0.z - u0.z) * inv; part += fmaxf(x, 0.f) * v0.z;
        x = bf2f(a8[3]) + bf2f(b8[3]) + w0.w + (t0.w - u0.w) * inv; part += fmaxf(x, 0.f) * v0.w;
        x = bf2f(a8[4]) + bf2f(b8[4]) + w1.x + (t1.x - u1.x) * inv; part += fmaxf(x, 0.f) * v1.x;
        x = bf2f(a8[5]) + bf2f(b8[5]) + w1.y + (t1.y - u1.y) * inv; part += fmaxf(x, 0.f) * v1.y;
        x = bf2f(a8[6]) + bf2f(b8[6]) + w1.z + (t1.z - u1.z) * inv; part += fmaxf(x, 0.f) * v1.z;
        x = bf2f(a8[7]) + bf2f(b8[7]) + w1.w + (t1.w - u1.w) * inv; part += fmaxf(x, 0.f) * v1.w;
    }
    #pragma unroll
    for (int off = 32; off > 0; off >>= 1) part += __shfl_down(part, off);
    if (lane == 0) out[c] = part + mlp2_b[0] + wscore[wi];
}

extern "C" void kernel_launch(void* const* d_in, const int* in_sizes, int n_in,
                              void* d_out, int out_size, void* d_ws, size_t ws_size,
                              hipStream_t stream) {
    const float* encoded_doc = (const float*)d_in[0];
    const int*   cand_starts = (const int*)d_in[1];
    const int*   cand_ends   = (const int*)d_in[2];
    const float* width_emb   = (const float*)d_in[3];
    const float* width_prior = (const float*)d_in[4];
    const float* attn_w      = (const float*)d_in[5];
    const float* attn_b      = (const float*)d_in[6];
    const float* mlp1_w      = (const float*)d_in[7];
    const float* mlp1_b      = (const float*)d_in[8];
    const float* mlp2_w      = (const float*)d_in[9];
    const float* mlp2_b      = (const float*)d_in[10];
    const float* wmlp1_w     = (const float*)d_in[11];
    const float* wmlp1_b     = (const float*)d_in[12];
    const float* wmlp2_w     = (const float*)d_in[13];
    const float* wmlp2_b     = (const float*)d_in[14];
    float* out = (float*)d_out;

    // workspace layout (float units from base; all large blocks 16B-aligned)
    float* Sbuf   = (float*)d_ws;                      // NW*1024
    float* T      = Sbuf + (size_t)NW * M;             // NCH*M = 65536
    float* PW     = T + NCH * M;                       // 30*1024
    float* ewa    = PW + MSW * M;                      // 4096
    float* Dpre   = ewa + NW;                          // 4160
    float* wscore = Dpre + 4160;                       // 64
    unsigned short* Pse  = (unsigned short*)(wscore + 64);      // NW*2048 bf16
    unsigned short* docb = Pse + (size_t)NW * 2048;             // NW*H bf16
    unsigned short* Btb  = docb + (size_t)NW * H;               // 3072*H bf16
    int* hist = (int*)(Btb + (size_t)3072 * H);        // 4096
    int* offs = hist + 4096;                           // 4096
    int* perm = offs + 4096;                           // NC

    k_doc_prep<<<NW / 4, 256, 0, stream>>>(encoded_doc, attn_w, attn_b, docb, ewa);
    k_cvt_bt<<<dim3(H / 32, M / 32, 3), 256, 0, stream>>>(mlp1_w, Btb);
    k_dscan<<<1, 256, 0, stream>>>(ewa, Dpre);
    k_pw<<<dim3(MSW, M / 256), 256, 0, stream>>>(width_emb, mlp1_w, mlp1_b, PW);
    k_wscore<<<MSW, 256, 0, stream>>>(width_prior, wmlp1_w, wmlp1_b, wmlp2_w, wmlp2_b, wscore);
    k_zero<<<NW / 256, 256, 0, stream>>>(hist);
    k_hist<<<NC / 256, 256, 0, stream>>>(cand_starts, hist);
    k_hscan<<<1, 256, 0, stream>>>(hist, offs);
    k_scatter<<<NC / 256, 256, 0, stream>>>(cand_starts, offs, perm);
    k_proj_mfma<<<dim3(3072 / 128, NW / 128), 256, 0, stream>>>(docb, Btb, Pse, Sbuf);
    k_scan1<<<dim3(M / 256, NCH), 256, 0, stream>>>(Sbuf, ewa, T);
    k_scan2<<<M / 256, 256, 0, stream>>>(T);
    k_scan3<<<dim3(M / 256, NCH), 256, 0, stream>>>(Sbuf, ewa, T);
    k_cand<<<NC / 4, 256, 0, stream>>>(Pse, Sbuf, PW, Dpre, wscore, perm,
                                       cand_starts, cand_ends, mlp2_w, mlp2_b, out);
}

// Round 5
// 139.040 us; speedup vs baseline: 4.7093x; 1.0058x over previous
//
#include <hip/hip_runtime.h>
#include <math.h>

#define NW 4096
#define H 768
#define NC 49152
#define MSW 30
#define E 20
#define M 1024
#define CHUNK 64
#define NCH (NW / CHUNK)
// Pse: bf16 [NW][2048] (cols 0:1024 start-proj, 1024:2048 end-proj)
// Sbuf: f32 [NW][1024] attn-proj, overwritten in place by exp-weighted prefix:
//   Sbuf[r][m] = S[r+1][m] = sum_{i<=r} ewa[i]*Pattn[i][m]

typedef short bf16x8 __attribute__((ext_vector_type(8)));
typedef unsigned short u16x8 __attribute__((ext_vector_type(8)));
typedef float f32x4 __attribute__((ext_vector_type(4)));

__device__ __forceinline__ unsigned short f2bf(float x) {
    unsigned u = __float_as_uint(x);
    return (unsigned short)((u + 0x7fff + ((u >> 16) & 1)) >> 16);  // RNE
}
__device__ __forceinline__ float bf2f(unsigned short b) {
    return __uint_as_float(((unsigned)b) << 16);
}
__device__ __forceinline__ void gload16(const void* g, void* l) {
    __builtin_amdgcn_global_load_lds((const __attribute__((address_space(1))) void*)g,
                                     (__attribute__((address_space(3))) void*)l, 16, 0, 0);
}

// ---------------- fused: docb = bf16(doc); ewa = exp(doc @ attn_w + b) ----------------
__global__ __launch_bounds__(256) void k_doc_prep(const float* __restrict__ doc,
                                                  const float* __restrict__ attn_w,
                                                  const float* __restrict__ attn_b,
                                                  unsigned short* __restrict__ docb,
                                                  float* __restrict__ ewa) {
    int row = blockIdx.x * 4 + (threadIdx.x >> 6);
    int lane = threadIdx.x & 63;
    const float* r = doc + (size_t)row * H;
    float s = 0.f;
    #pragma unroll
    for (int q = 0; q < 3; ++q) {
        int idx = q * 256 + lane * 4;
        float4 v = *reinterpret_cast<const float4*>(r + idx);
        float4 w = *reinterpret_cast<const float4*>(attn_w + idx);
        s += v.x * w.x + v.y * w.y + v.z * w.z + v.w * w.w;
        ushort4 o;
        o.x = f2bf(v.x); o.y = f2bf(v.y); o.z = f2bf(v.z); o.w = f2bf(v.w);
        *reinterpret_cast<ushort4*>(docb + (size_t)row * H + idx) = o;
    }
    #pragma unroll
    for (int off = 32; off > 0; off >>= 1) s += __shfl_down(s, off);
    if (lane == 0) ewa[row] = expf(s + attn_b[0]);
}

// ---------------- Bt[col][k] = bf16(mlp1_w[rb(part)+k][m]), col = part*1024+m ----------------
__global__ __launch_bounds__(256) void k_cvt_bt(const float* __restrict__ mlp1_w,
                                                unsigned short* __restrict__ Bt) {
    __shared__ float sh[32][33];
    int k0 = blockIdx.x * 32, m0 = blockIdx.y * 32, part = blockIdx.z;
    int rb = part == 0 ? 0 : (part == 1 ? H : (2 * H + E));
    int tx = threadIdx.x & 31, ty = threadIdx.x >> 5;
    #pragma unroll
    for (int it = 0; it < 4; ++it) {
        int kk = ty + it * 8;
        sh[kk][tx] = mlp1_w[(size_t)(rb + k0 + kk) * M + m0 + tx];
    }
    __syncthreads();
    #pragma unroll
    for (int it = 0; it < 4; ++it) {
        int mm = ty + it * 8;
        Bt[(size_t)(part * M + m0 + mm) * H + k0 + tx] = f2bf(sh[tx][mm]);
    }
}

// ---------------- Dpre[i] = sum_{j<i} ewa[j] ----------------
__global__ __launch_bounds__(256) void k_dscan(const float* __restrict__ ewa,
                                               float* __restrict__ Dpre) {
    int t = threadIdx.x;
    float v[16];
    float sum = 0.f;
    #pragma unroll
    for (int i = 0; i < 16; ++i) { v[i] = ewa[t * 16 + i]; sum += v[i]; }
    __shared__ float sh[256];
    sh[t] = sum;
    __syncthreads();
    for (int off = 1; off < 256; off <<= 1) {
        float x = (t >= off) ? sh[t - off] : 0.f;
        __syncthreads();
        sh[t] += x;
        __syncthreads();
    }
    float run = sh[t] - sum;
    #pragma unroll
    for (int i = 0; i < 16; ++i) { run += v[i]; Dpre[t * 16 + i + 1] = run; }
    if (t == 0) Dpre[0] = 0.f;
}

// ---------------- PW[w][m] = width_emb[w] @ W1[2H:2H+E] + mlp1_b ----------------
__global__ __launch_bounds__(256) void k_pw(const float* __restrict__ width_emb,
                                            const float* __restrict__ mlp1_w,
                                            const float* __restrict__ mlp1_b,
                                            float* __restrict__ PW) {
    int w = blockIdx.x;
    int m = blockIdx.y * 256 + threadIdx.x;
    float acc = mlp1_b[m];
    #pragma unroll
    for (int e = 0; e < E; ++e)
        acc += width_emb[w * E + e] * mlp1_w[(size_t)(2 * H + e) * M + m];
    PW[w * M + m] = acc;
}

// ---------------- wscore[w] ----------------
__global__ __launch_bounds__(256) void k_wscore(const float* __restrict__ wp_emb,
                                                const float* __restrict__ w1,
                                                const float* __restrict__ b1,
                                                const float* __restrict__ w2,
                                                const float* __restrict__ b2,
                                                float* __restrict__ wscore) {
    int w = blockIdx.x;
    int tid = threadIdx.x;
    float part = 0.f;
    for (int m = tid; m < M; m += 256) {
        float h = b1[m];
        #pragma unroll
        for (int e = 0; e < E; ++e) h += wp_emb[w * E + e] * w1[e * M + m];
        part += fmaxf(h, 0.f) * w2[m];
    }
    __shared__ float red[256];
    red[tid] = part;
    __syncthreads();
    for (int s = 128; s > 0; s >>= 1) {
        if (tid < s) red[tid] += red[tid + s];
        __syncthreads();
    }
    if (tid == 0) wscore[w] = red[0] + b2[0];
}

// ---------------- sort-by-start: zero / hist / exclusive-scan / scatter ----------------
__global__ __launch_bounds__(256) void k_zero(int* __restrict__ hist) {
    hist[blockIdx.x * 256 + threadIdx.x] = 0;
}
__global__ __launch_bounds__(256) void k_hist(const int* __restrict__ starts,
                                              int* __restrict__ hist) {
    atomicAdd(&hist[starts[blockIdx.x * 256 + threadIdx.x]], 1);
}
__global__ __launch_bounds__(256) void k_hscan(const int* __restrict__ hist,
                                               int* __restrict__ offs) {
    int t = threadIdx.x;
    int v[16];
    int sum = 0;
    #pragma unroll
    for (int i = 0; i < 16; ++i) { v[i] = hist[t * 16 + i]; sum += v[i]; }
    __shared__ int sh[256];
    sh[t] = sum;
    __syncthreads();
    for (int off = 1; off < 256; off <<= 1) {
        int x = (t >= off) ? sh[t - off] : 0;
        __syncthreads();
        sh[t] += x;
        __syncthreads();
    }
    int run = sh[t] - sum;
    #pragma unroll
    for (int i = 0; i < 16; ++i) { offs[t * 16 + i] = run; run += v[i]; }
}
__global__ __launch_bounds__(256) void k_scatter(const int* __restrict__ starts,
                                                 int* __restrict__ offs,
                                                 int* __restrict__ perm) {
    int c = blockIdx.x * 256 + threadIdx.x;
    int p = atomicAdd(&offs[starts[c]], 1);
    perm[p] = c;
}

// ---------------- MFMA projection, double-buffered issue-early staging ----------------
// A tile 128x64 bf16, B tile 64x128 bf16, fragment-ordered LDS (all ds_reads linear).
// Stage for K-tile t+1 is ISSUED before computing tile t; the trailing
// __syncthreads() (vmcnt(0)) then drains a load whose latency hid under compute.
__global__ __launch_bounds__(256) void k_proj_mfma(const unsigned short* __restrict__ docb,
                                                   const unsigned short* __restrict__ Bt,
                                                   unsigned short* __restrict__ Pse,
                                                   float* __restrict__ Sbuf) {
    __shared__ unsigned short As[2][8192];  // [buf][R16:8][ks:2][g:4][ri:16][j:8]
    __shared__ unsigned short Bs[2][8192];
    int tid = threadIdx.x;
    int col0 = blockIdx.x * 128;
    int row0 = blockIdx.y * 128;
    int part = col0 >> 10;
    int cbase = col0 & 1023;
    int wv = tid >> 6, lane = tid & 63;
    int wr = wv >> 1, wc = wv & 1;

    // per-thread staging coords (constant across K-steps)
    int s0 = tid;          // covers s = tid, 256+tid, 512+tid, 768+tid
    f32x4 acc[4][4];
    #pragma unroll
    for (int mi = 0; mi < 4; ++mi)
        #pragma unroll
        for (int ni = 0; ni < 4; ++ni) acc[mi][ni] = (f32x4){0.f, 0.f, 0.f, 0.f};

    #define STAGE(buf, k0)                                                          \
        {                                                                           \
            _Pragma("unroll")                                                       \
            for (int i = 0; i < 4; ++i) {                                           \
                int s = i * 256 + s0;                                               \
                int rr = s >> 7;                                                    \
                int ks = (s >> 6) & 1;                                              \
                int g  = (s >> 4) & 3;                                              \
                int ri = s & 15;                                                    \
                int kloc = (k0) + ks * 32 + g * 8;                                  \
                gload16(docb + (size_t)(row0 + rr * 16 + ri) * H + kloc,            \
                        (char*)As[buf] + s * 16);                                   \
                gload16(Bt   + (size_t)(col0 + rr * 16 + ri) * H + kloc,            \
                        (char*)Bs[buf] + s * 16);                                   \
            }                                                                       \
        }

    STAGE(0, 0);
    __syncthreads();  // vmcnt(0) drain: buf0 ready

    #pragma unroll 1
    for (int t = 0; t < H / 64; ++t) {
        int cur = t & 1;
        if (t + 1 < H / 64) STAGE(cur ^ 1, (t + 1) * 64);  // issue-early: latency hides under compute
        #pragma unroll
        for (int ks = 0; ks < 2; ++ks) {
            bf16x8 af[4], bfr[4];
            #pragma unroll
            for (int mi = 0; mi < 4; ++mi)
                af[mi] = *reinterpret_cast<const bf16x8*>(
                    (char*)As[cur] + (wr * 4 + mi) * 2048 + ks * 1024 + lane * 16);
            #pragma unroll
            for (int ni = 0; ni < 4; ++ni)
                bfr[ni] = *reinterpret_cast<const bf16x8*>(
                    (char*)Bs[cur] + (wc * 4 + ni) * 2048 + ks * 1024 + lane * 16);
            #pragma unroll
            for (int mi = 0; mi < 4; ++mi)
                #pragma unroll
                for (int ni = 0; ni < 4; ++ni)
                    acc[mi][ni] = __builtin_amdgcn_mfma_f32_16x16x32_bf16(
                        af[mi], bfr[ni], acc[mi][ni], 0, 0, 0);
        }
        __syncthreads();  // drains next-tile stage (latency already overlapped) + LDS reuse fence
    }
    #undef STAGE

    int cr = (lane >> 4) * 4;
    int cc = lane & 15;
    #pragma unroll
    for (int mi = 0; mi < 4; ++mi) {
        #pragma unroll
        for (int ni = 0; ni < 4; ++ni) {
            int r = row0 + wr * 64 + mi * 16 + cr;
            int c = cbase + wc * 64 + ni * 16 + cc;
            if (part < 2) {
                unsigned short* dst = Pse + (size_t)r * 2048 + part * 1024 + c;
                #pragma unroll
                for (int j = 0; j < 4; ++j) dst[(size_t)j * 2048] = f2bf(acc[mi][ni][j]);
            } else {
                float* dst = Sbuf + (size_t)r * M + c;
                #pragma unroll
                for (int j = 0; j < 4; ++j) dst[(size_t)j * M] = acc[mi][ni][j];
            }
        }
    }
}

// ---------------- scan phase 1: per-chunk totals of ewa[i]*Pattn[i][m] ----------------
__global__ __launch_bounds__(256) void k_scan1(const float* __restrict__ Sbuf,
                                               const float* __restrict__ ewa,
                                               float* __restrict__ T) {
    int m = blockIdx.x * 256 + threadIdx.x;
    int c = blockIdx.y;
    __shared__ float ew[CHUNK];
    if (threadIdx.x < CHUNK) ew[threadIdx.x] = ewa[c * CHUNK + threadIdx.x];
    __syncthreads();
    const float* base = Sbuf + (size_t)(c * CHUNK) * M + m;
    float acc = 0.f;
    #pragma unroll 8
    for (int i = 0; i < CHUNK; ++i)
        acc += ew[i] * base[(size_t)i * M];
    T[c * M + m] = acc;
}

// ---------------- scan phase 2: exclusive scan of chunk totals (reg-resident) ----------------
__global__ __launch_bounds__(256) void k_scan2(float* __restrict__ T) {
    int m = blockIdx.x * 256 + threadIdx.x;
    float v[NCH];
    #pragma unroll
    for (int c = 0; c < NCH; ++c) v[c] = T[c * M + m];
    float run = 0.f;
    #pragma unroll
    for (int c = 0; c < NCH; ++c) { float t = v[c]; T[c * M + m] = run; run += t; }
}

// ---------------- scan phase 3: in-place inclusive prefix over Sbuf ----------------
__global__ __launch_bounds__(256) void k_scan3(float* __restrict__ Sbuf,
                                               const float* __restrict__ ewa,
                                               const float* __restrict__ T) {
    int m = blockIdx.x * 256 + threadIdx.x;
    int c = blockIdx.y;
    __shared__ float ew[CHUNK];
    if (threadIdx.x < CHUNK) ew[threadIdx.x] = ewa[c * CHUNK + threadIdx.x];
    __syncthreads();
    float acc = T[c * M + m];
    float* base = Sbuf + (size_t)(c * CHUNK) * M + m;
    #pragma unroll 4
    for (int i = 0; i < CHUNK; ++i) {
        float* p = base + (size_t)i * M;
        acc += ew[i] * (*p);
        *p = acc;
    }
}

// ---------------- per-candidate scoring (sorted order, XCD-swizzled) ----------------
__global__ __launch_bounds__(256) void k_cand(const unsigned short* __restrict__ Pse,
                                              const float* __restrict__ Sbuf,
                                              const float* __restrict__ PW,
                                              const float* __restrict__ Dpre,
                                              const float* __restrict__ wscore,
                                              const int* __restrict__ perm,
                                              const int* __restrict__ starts,
                                              const int* __restrict__ ends,
                                              const float* __restrict__ mlp2_w,
                                              const float* __restrict__ mlp2_b,
                                              float* __restrict__ out) {
    int bid = blockIdx.x;                                   // 12288 blocks, %8==0 -> bijective
    int eff = (bid & 7) * (12288 / 8) + (bid >> 3);         // XCD-contiguous sorted ranges
    int j = eff * 4 + (threadIdx.x >> 6);
    int lane = threadIdx.x & 63;
    int c = perm[j];
    int s = starts[c], e = ends[c];
    int wi = e - s;
    wi = wi < 0 ? 0 : (wi > MSW - 1 ? MSW - 1 : wi);

    float inv = 1.f / (Dpre[e + 1] - Dpre[s]);

    const unsigned short* ps = Pse + (size_t)s * 2048;
    const unsigned short* pe = Pse + (size_t)e * 2048 + 1024;
    const float* se = Sbuf + (size_t)e * M;                 // S[e+1]
    const float* ss = Sbuf + (size_t)(s > 0 ? s - 1 : 0) * M;  // S[s]
    const float* pw = PW + (size_t)wi * M;
    bool has_s = (s > 0);

    float part = 0.f;
    #pragma unroll
    for (int q = 0; q < 2; ++q) {
        int m = lane * 8 + q * 512;
        u16x8 a8 = *reinterpret_cast<const u16x8*>(ps + m);
        u16x8 b8 = *reinterpret_cast<const u16x8*>(pe + m);
        float4 t0 = *reinterpret_cast<const float4*>(se + m);
        float4 t1 = *reinterpret_cast<const float4*>(se + m + 4);
        float4 u0 = make_float4(0.f, 0.f, 0.f, 0.f), u1 = u0;
        if (has_s) {
            u0 = *reinterpret_cast<const float4*>(ss + m);
            u1 = *reinterpret_cast<const float4*>(ss + m + 4);
        }
        float4 w0 = *reinterpret_cast<const float4*>(pw + m);
        float4 w1 = *reinterpret_cast<const float4*>(pw + m + 4);
        float4 v0 = *reinterpret_cast<const float4*>(mlp2_w + m);
        float4 v1 = *reinterpret_cast<const float4*>(mlp2_w + m + 4);
        float x;
        x = bf2f(a8[0]) + bf2f(b8[0]) + w0.x + (t0.x - u0.x) * inv; part += fmaxf(x, 0.f) * v0.x;
        x = bf2f(a8[1]) + bf2f(b8[1]) + w0.y + (t0.y - u0.y) * inv; part += fmaxf(x, 0.f) * v0.y;
        x = bf2f(a8[2]) + bf2f(b8[2]) + w0.z + (t0.z - u0.z) * inv; part += fmaxf(x, 0.f) * v0.z;
        x = bf2f(a8[3]) + bf2f(b8[3]) + w0.w + (t0.w - u0.w) * inv; part += fmaxf(x, 0.f) * v0.w;
        x = bf2f(a8[4]) + bf2f(b8[4]) + w1.x + (t1.x - u1.x) * inv; part += fmaxf(x, 0.f) * v1.x;
        x = bf2f(a8[5]) + bf2f(b8[5]) + w1.y + (t1.y - u1.y) * inv; part += fmaxf(x, 0.f) * v1.y;
        x = bf2f(a8[6]) + bf2f(b8[6]) + w1.z + (t1.z - u1.z) * inv; part += fmaxf(x, 0.f) * v1.z;
        x = bf2f(a8[7]) + bf2f(b8[7]) + w1.w + (t1.w - u1.w) * inv; part += fmaxf(x, 0.f) * v1.w;
    }
    #pragma unroll
    for (int off = 32; off > 0; off >>= 1) part += __shfl_down(part, off);
    if (lane == 0) out[c] = part + mlp2_b[0] + wscore[wi];
}

extern "C" void kernel_launch(void* const* d_in, const int* in_sizes, int n_in,
                              void* d_out, int out_size, void* d_ws, size_t ws_size,
                              hipStream_t stream) {
    const float* encoded_doc = (const float*)d_in[0];
    const int*   cand_starts = (const int*)d_in[1];
    const int*   cand_ends   = (const int*)d_in[2];
    const float* width_emb   = (const float*)d_in[3];
    const float* width_prior = (const float*)d_in[4];
    const float* attn_w      = (const float*)d_in[5];
    const float* attn_b      = (const float*)d_in[6];
    const float* mlp1_w      = (const float*)d_in[7];
    const float* mlp1_b      = (const float*)d_in[8];
    const float* mlp2_w      = (const float*)d_in[9];
    const float* mlp2_b      = (const float*)d_in[10];
    const float* wmlp1_w     = (const float*)d_in[11];
    const float* wmlp1_b     = (const float*)d_in[12];
    const float* wmlp2_w     = (const float*)d_in[13];
    const float* wmlp2_b     = (const float*)d_in[14];
    float* out = (float*)d_out;

    // workspace layout (float units from base; all large blocks 16B-aligned)
    float* Sbuf   = (float*)d_ws;                      // NW*1024
    float* T      = Sbuf + (size_t)NW * M;             // NCH*M = 65536
    float* PW     = T + NCH * M;                       // 30*1024
    float* ewa    = PW + MSW * M;                      // 4096
    float* Dpre   = ewa + NW;                          // 4160
    float* wscore = Dpre + 4160;                       // 64
    unsigned short* Pse  = (unsigned short*)(wscore + 64);      // NW*2048 bf16
    unsigned short* docb = Pse + (size_t)NW * 2048;             // NW*H bf16
    unsigned short* Btb  = docb + (size_t)NW * H;               // 3072*H bf16
    int* hist = (int*)(Btb + (size_t)3072 * H);        // 4096
    int* offs = hist + 4096;                           // 4096
    int* perm = offs + 4096;                           // NC

    k_doc_prep<<<NW / 4, 256, 0, stream>>>(encoded_doc, attn_w, attn_b, docb, ewa);
    k_cvt_bt<<<dim3(H / 32, M / 32, 3), 256, 0, stream>>>(mlp1_w, Btb);
    k_dscan<<<1, 256, 0, stream>>>(ewa, Dpre);
    k_pw<<<dim3(MSW, M / 256), 256, 0, stream>>>(width_emb, mlp1_w, mlp1_b, PW);
    k_wscore<<<MSW, 256, 0, stream>>>(width_prior, wmlp1_w, wmlp1_b, wmlp2_w, wmlp2_b, wscore);
    k_zero<<<NW / 256, 256, 0, stream>>>(hist);
    k_hist<<<NC / 256, 256, 0, stream>>>(cand_starts, hist);
    k_hscan<<<1, 256, 0, stream>>>(hist, offs);
    k_scatter<<<NC / 256, 256, 0, stream>>>(cand_starts, offs, perm);
    k_proj_mfma<<<dim3(3072 / 128, NW / 128), 256, 0, stream>>>(docb, Btb, Pse, Sbuf);
    k_scan1<<<dim3(M / 256, NCH), 256, 0, stream>>>(Sbuf, ewa, T);
    k_scan2<<<M / 256, 256, 0, stream>>>(T);
    k_scan3<<<dim3(M / 256, NCH), 256, 0, stream>>>(Sbuf, ewa, T);
    k_cand<<<NC / 4, 256, 0, stream>>>(Pse, Sbuf, PW, Dpre, wscore, perm,
                                       cand_starts, cand_ends, mlp2_w, mlp2_b, out);
}

// Round 6
// 135.993 us; speedup vs baseline: 4.8149x; 1.0224x over previous
//
#include <hip/hip_runtime.h>
#include <math.h>

#define NW 4096
#define H 768
#define NC 49152
#define MSW 30
#define E 20
#define M 1024
#define CHUNK 64
#define NCH (NW / CHUNK)
#define NKT (H / 64)   // 12 K-tiles
// Pse: bf16 [NW][2048] (cols 0:1024 start-proj, 1024:2048 end-proj)
// Sbuf: f32 [NW][1024] attn-proj, overwritten in place by exp-weighted prefix:
//   Sbuf[r][m] = S[r+1][m] = sum_{i<=r} ewa[i]*Pattn[i][m]

typedef short bf16x8 __attribute__((ext_vector_type(8)));
typedef unsigned short u16x8 __attribute__((ext_vector_type(8)));
typedef float f32x4 __attribute__((ext_vector_type(4)));

__device__ __forceinline__ unsigned short f2bf(float x) {
    unsigned u = __float_as_uint(x);
    return (unsigned short)((u + 0x7fff + ((u >> 16) & 1)) >> 16);  // RNE
}
__device__ __forceinline__ float bf2f(unsigned short b) {
    return __uint_as_float(((unsigned)b) << 16);
}
__device__ __forceinline__ void gload16(const void* g, void* l) {
    __builtin_amdgcn_global_load_lds((const __attribute__((address_space(1))) void*)g,
                                     (__attribute__((address_space(3))) void*)l, 16, 0, 0);
}

// ---------------- fused: docb = bf16(doc); ewa = exp(doc @ attn_w + b) ----------------
__global__ __launch_bounds__(256) void k_doc_prep(const float* __restrict__ doc,
                                                  const float* __restrict__ attn_w,
                                                  const float* __restrict__ attn_b,
                                                  unsigned short* __restrict__ docb,
                                                  float* __restrict__ ewa) {
    int row = blockIdx.x * 4 + (threadIdx.x >> 6);
    int lane = threadIdx.x & 63;
    const float* r = doc + (size_t)row * H;
    float s = 0.f;
    #pragma unroll
    for (int q = 0; q < 3; ++q) {
        int idx = q * 256 + lane * 4;
        float4 v = *reinterpret_cast<const float4*>(r + idx);
        float4 w = *reinterpret_cast<const float4*>(attn_w + idx);
        s += v.x * w.x + v.y * w.y + v.z * w.z + v.w * w.w;
        ushort4 o;
        o.x = f2bf(v.x); o.y = f2bf(v.y); o.z = f2bf(v.z); o.w = f2bf(v.w);
        *reinterpret_cast<ushort4*>(docb + (size_t)row * H + idx) = o;
    }
    #pragma unroll
    for (int off = 32; off > 0; off >>= 1) s += __shfl_down(s, off);
    if (lane == 0) ewa[row] = expf(s + attn_b[0]);
}

// ---------------- Bt[col][k] = bf16(mlp1_w[rb(part)+k][m]), col = part*1024+m ----------------
__global__ __launch_bounds__(256) void k_cvt_bt(const float* __restrict__ mlp1_w,
                                                unsigned short* __restrict__ Bt) {
    __shared__ float sh[32][33];
    int k0 = blockIdx.x * 32, m0 = blockIdx.y * 32, part = blockIdx.z;
    int rb = part == 0 ? 0 : (part == 1 ? H : (2 * H + E));
    int tx = threadIdx.x & 31, ty = threadIdx.x >> 5;
    #pragma unroll
    for (int it = 0; it < 4; ++it) {
        int kk = ty + it * 8;
        sh[kk][tx] = mlp1_w[(size_t)(rb + k0 + kk) * M + m0 + tx];
    }
    __syncthreads();
    #pragma unroll
    for (int it = 0; it < 4; ++it) {
        int mm = ty + it * 8;
        Bt[(size_t)(part * M + m0 + mm) * H + k0 + tx] = f2bf(sh[tx][mm]);
    }
}

// ---------------- Dpre[i] = sum_{j<i} ewa[j] ----------------
__global__ __launch_bounds__(256) void k_dscan(const float* __restrict__ ewa,
                                               float* __restrict__ Dpre) {
    int t = threadIdx.x;
    float v[16];
    float sum = 0.f;
    #pragma unroll
    for (int i = 0; i < 16; ++i) { v[i] = ewa[t * 16 + i]; sum += v[i]; }
    __shared__ float sh[256];
    sh[t] = sum;
    __syncthreads();
    for (int off = 1; off < 256; off <<= 1) {
        float x = (t >= off) ? sh[t - off] : 0.f;
        __syncthreads();
        sh[t] += x;
        __syncthreads();
    }
    float run = sh[t] - sum;
    #pragma unroll
    for (int i = 0; i < 16; ++i) { run += v[i]; Dpre[t * 16 + i + 1] = run; }
    if (t == 0) Dpre[0] = 0.f;
}

// ---------------- PW[w][m] = width_emb[w] @ W1[2H:2H+E] + mlp1_b ----------------
__global__ __launch_bounds__(256) void k_pw(const float* __restrict__ width_emb,
                                            const float* __restrict__ mlp1_w,
                                            const float* __restrict__ mlp1_b,
                                            float* __restrict__ PW) {
    int w = blockIdx.x;
    int m = blockIdx.y * 256 + threadIdx.x;
    float acc = mlp1_b[m];
    #pragma unroll
    for (int e = 0; e < E; ++e)
        acc += width_emb[w * E + e] * mlp1_w[(size_t)(2 * H + e) * M + m];
    PW[w * M + m] = acc;
}

// ---------------- wscore[w] ----------------
__global__ __launch_bounds__(256) void k_wscore(const float* __restrict__ wp_emb,
                                                const float* __restrict__ w1,
                                                const float* __restrict__ b1,
                                                const float* __restrict__ w2,
                                                const float* __restrict__ b2,
                                                float* __restrict__ wscore) {
    int w = blockIdx.x;
    int tid = threadIdx.x;
    float part = 0.f;
    for (int m = tid; m < M; m += 256) {
        float h = b1[m];
        #pragma unroll
        for (int e = 0; e < E; ++e) h += wp_emb[w * E + e] * w1[e * M + m];
        part += fmaxf(h, 0.f) * w2[m];
    }
    __shared__ float red[256];
    red[tid] = part;
    __syncthreads();
    for (int s = 128; s > 0; s >>= 1) {
        if (tid < s) red[tid] += red[tid + s];
        __syncthreads();
    }
    if (tid == 0) wscore[w] = red[0] + b2[0];
}

// ---------------- sort-by-start: zero / hist / exclusive-scan / scatter ----------------
__global__ __launch_bounds__(256) void k_zero(int* __restrict__ hist) {
    hist[blockIdx.x * 256 + threadIdx.x] = 0;
}
__global__ __launch_bounds__(256) void k_hist(const int* __restrict__ starts,
                                              int* __restrict__ hist) {
    atomicAdd(&hist[starts[blockIdx.x * 256 + threadIdx.x]], 1);
}
__global__ __launch_bounds__(256) void k_hscan(const int* __restrict__ hist,
                                               int* __restrict__ offs) {
    int t = threadIdx.x;
    int v[16];
    int sum = 0;
    #pragma unroll
    for (int i = 0; i < 16; ++i) { v[i] = hist[t * 16 + i]; sum += v[i]; }
    __shared__ int sh[256];
    sh[t] = sum;
    __syncthreads();
    for (int off = 1; off < 256; off <<= 1) {
        int x = (t >= off) ? sh[t - off] : 0;
        __syncthreads();
        sh[t] += x;
        __syncthreads();
    }
    int run = sh[t] - sum;
    #pragma unroll
    for (int i = 0; i < 16; ++i) { offs[t * 16 + i] = run; run += v[i]; }
}
__global__ __launch_bounds__(256) void k_scatter(const int* __restrict__ starts,
                                                 int* __restrict__ offs,
                                                 int* __restrict__ perm) {
    int c = blockIdx.x * 256 + threadIdx.x;
    int p = atomicAdd(&offs[starts[c]], 1);
    perm[p] = c;
}

// ---------------- MFMA projection: counted-vmcnt 2-deep pipeline + XCD supertiles --------
// A tile 128x64 bf16, B tile 64x128 bf16, fragment-ordered LDS (linear ds_reads).
// Pipeline: tiles t+1,t+2 in flight; per-iter waits are lgkmcnt(0) (own LDS reads
// retired, fences buffer overwrite) and vmcnt(8) (tile t+1 landed; t+2 stays in
// flight ACROSS the barrier). vmcnt(0) only at the pipeline drain (t=NKT-2).
__global__ __launch_bounds__(256) void k_proj_mfma(const unsigned short* __restrict__ docb,
                                                   const unsigned short* __restrict__ Bt,
                                                   unsigned short* __restrict__ Pse,
                                                   float* __restrict__ Sbuf) {
    __shared__ unsigned short As[2][8192];  // [buf][R16:8][ks:2][g:4][ri:16][j:8]
    __shared__ unsigned short Bs[2][8192];
    int tid = threadIdx.x;
    // XCD-bijective supertile map: each XCD owns 12 col-tiles x 8 row-tiles ->
    // per-XCD footprint 2.25MB Bt + 1.5MB docb = 3.75MB < 4MB L2.
    int bid = blockIdx.x;              // 768 blocks
    int xcd = bid & 7, r = bid >> 3;   // r: 0..95
    int col0 = ((xcd & 1) * 12 + (r % 12)) * 128;   // 0..23 tiles
    int row0 = ((xcd >> 1) * 8 + (r / 12)) * 128;   // 0..31 tiles
    int part = col0 >> 10;
    int cbase = col0 & 1023;
    int wv = tid >> 6, lane = tid & 63;
    int wr = wv >> 1, wc = wv & 1;

    f32x4 acc[4][4];
    #pragma unroll
    for (int mi = 0; mi < 4; ++mi)
        #pragma unroll
        for (int ni = 0; ni < 4; ++ni) acc[mi][ni] = (f32x4){0.f, 0.f, 0.f, 0.f};

    // 8 gload16 per thread per STAGE -> vmcnt(8) == "previous tile's loads done"
    #define STAGE(buf, k0)                                                          \
        {                                                                           \
            _Pragma("unroll")                                                       \
            for (int i = 0; i < 4; ++i) {                                           \
                int s = i * 256 + tid;                                              \
                int rr = s >> 7;                                                    \
                int ks = (s >> 6) & 1;                                              \
                int g  = (s >> 4) & 3;                                              \
                int ri = s & 15;                                                    \
                int kloc = (k0) + ks * 32 + g * 8;                                  \
                gload16(docb + (size_t)(row0 + rr * 16 + ri) * H + kloc,            \
                        (char*)As[buf] + s * 16);                                   \
                gload16(Bt   + (size_t)(col0 + rr * 16 + ri) * H + kloc,            \
                        (char*)Bs[buf] + s * 16);                                   \
            }                                                                       \
        }

    STAGE(0, 0);
    STAGE(1, 64);
    asm volatile("s_waitcnt vmcnt(8)" ::: "memory");  // tile 0 landed (tile 1 in flight)
    __builtin_amdgcn_s_barrier();

    #pragma unroll 1
    for (int t = 0; t < NKT; ++t) {
        int cur = t & 1;
        bf16x8 af[2][4], bfr[2][4];
        #pragma unroll
        for (int ks = 0; ks < 2; ++ks) {
            #pragma unroll
            for (int mi = 0; mi < 4; ++mi)
                af[ks][mi] = *reinterpret_cast<const bf16x8*>(
                    (char*)As[cur] + (wr * 4 + mi) * 2048 + ks * 1024 + lane * 16);
            #pragma unroll
            for (int ni = 0; ni < 4; ++ni)
                bfr[ks][ni] = *reinterpret_cast<const bf16x8*>(
                    (char*)Bs[cur] + (wc * 4 + ni) * 2048 + ks * 1024 + lane * 16);
        }
        asm volatile("s_waitcnt lgkmcnt(0)" ::: "memory");  // own reads retired
        __builtin_amdgcn_s_barrier();                       // all waves done with buf[cur]
        if (t + 2 < NKT) STAGE(cur, (t + 2) * 64);          // overwrite buf[cur] w/ tile t+2
        #pragma unroll
        for (int ks = 0; ks < 2; ++ks)
            #pragma unroll
            for (int mi = 0; mi < 4; ++mi)
                #pragma unroll
                for (int ni = 0; ni < 4; ++ni)
                    acc[mi][ni] = __builtin_amdgcn_mfma_f32_16x16x32_bf16(
                        af[ks][mi], bfr[ks][ni], acc[mi][ni], 0, 0, 0);
        if (t + 2 < NKT) {
            asm volatile("s_waitcnt vmcnt(8)" ::: "memory");  // tile t+1 landed, t+2 in flight
            __builtin_amdgcn_s_barrier();
        } else if (t + 2 == NKT) {
            asm volatile("s_waitcnt vmcnt(0)" ::: "memory");  // drain: last tile landed
            __builtin_amdgcn_s_barrier();
        }
        // t == NKT-1: no further LDS use
    }
    #undef STAGE

    int cr = (lane >> 4) * 4;
    int cc = lane & 15;
    #pragma unroll
    for (int mi = 0; mi < 4; ++mi) {
        #pragma unroll
        for (int ni = 0; ni < 4; ++ni) {
            int rr2 = row0 + wr * 64 + mi * 16 + cr;
            int c = cbase + wc * 64 + ni * 16 + cc;
            if (part < 2) {
                unsigned short* dst = Pse + (size_t)rr2 * 2048 + part * 1024 + c;
                #pragma unroll
                for (int j = 0; j < 4; ++j) dst[(size_t)j * 2048] = f2bf(acc[mi][ni][j]);
            } else {
                float* dst = Sbuf + (size_t)rr2 * M + c;
                #pragma unroll
                for (int j = 0; j < 4; ++j) dst[(size_t)j * M] = acc[mi][ni][j];
            }
        }
    }
}

// ---------------- scan phase 1: per-chunk totals of ewa[i]*Pattn[i][m] ----------------
__global__ __launch_bounds__(256) void k_scan1(const float* __restrict__ Sbuf,
                                               const float* __restrict__ ewa,
                                               float* __restrict__ T) {
    int m = blockIdx.x * 256 + threadIdx.x;
    int c = blockIdx.y;
    __shared__ float ew[CHUNK];
    if (threadIdx.x < CHUNK) ew[threadIdx.x] = ewa[c * CHUNK + threadIdx.x];
    __syncthreads();
    const float* base = Sbuf + (size_t)(c * CHUNK) * M + m;
    float acc = 0.f;
    #pragma unroll 8
    for (int i = 0; i < CHUNK; ++i)
        acc += ew[i] * base[(size_t)i * M];
    T[c * M + m] = acc;
}

// ---------------- scan phase 2: exclusive scan of chunk totals (reg-resident) ----------------
__global__ __launch_bounds__(256) void k_scan2(float* __restrict__ T) {
    int m = blockIdx.x * 256 + threadIdx.x;
    float v[NCH];
    #pragma unroll
    for (int c = 0; c < NCH; ++c) v[c] = T[c * M + m];
    float run = 0.f;
    #pragma unroll
    for (int c = 0; c < NCH; ++c) { float t = v[c]; T[c * M + m] = run; run += t; }
}

// ---------------- scan phase 3: in-place inclusive prefix over Sbuf ----------------
__global__ __launch_bounds__(256) void k_scan3(float* __restrict__ Sbuf,
                                               const float* __restrict__ ewa,
                                               const float* __restrict__ T) {
    int m = blockIdx.x * 256 + threadIdx.x;
    int c = blockIdx.y;
    __shared__ float ew[CHUNK];
    if (threadIdx.x < CHUNK) ew[threadIdx.x] = ewa[c * CHUNK + threadIdx.x];
    __syncthreads();
    float acc = T[c * M + m];
    float* base = Sbuf + (size_t)(c * CHUNK) * M + m;
    #pragma unroll 4
    for (int i = 0; i < CHUNK; ++i) {
        float* p = base + (size_t)i * M;
        acc += ew[i] * (*p);
        *p = acc;
    }
}

// ---------------- per-candidate scoring (sorted order, XCD-swizzled) ----------------
__global__ __launch_bounds__(256) void k_cand(const unsigned short* __restrict__ Pse,
                                              const float* __restrict__ Sbuf,
                                              const float* __restrict__ PW,
                                              const float* __restrict__ Dpre,
                                              const float* __restrict__ wscore,
                                              const int* __restrict__ perm,
                                              const int* __restrict__ starts,
                                              const int* __restrict__ ends,
                                              const float* __restrict__ mlp2_w,
                                              const float* __restrict__ mlp2_b,
                                              float* __restrict__ out) {
    int bid = blockIdx.x;                                   // 12288 blocks, %8==0 -> bijective
    int eff = (bid & 7) * (12288 / 8) + (bid >> 3);         // XCD-contiguous sorted ranges
    int j = eff * 4 + (threadIdx.x >> 6);
    int lane = threadIdx.x & 63;
    int c = perm[j];
    int s = starts[c], e = ends[c];
    int wi = e - s;
    wi = wi < 0 ? 0 : (wi > MSW - 1 ? MSW - 1 : wi);

    float inv = 1.f / (Dpre[e + 1] - Dpre[s]);

    const unsigned short* ps = Pse + (size_t)s * 2048;
    const unsigned short* pe = Pse + (size_t)e * 2048 + 1024;
    const float* se = Sbuf + (size_t)e * M;                 // S[e+1]
    const float* ss = Sbuf + (size_t)(s > 0 ? s - 1 : 0) * M;  // S[s]
    const float* pw = PW + (size_t)wi * M;
    bool has_s = (s > 0);

    float part = 0.f;
    #pragma unroll
    for (int q = 0; q < 2; ++q) {
        int m = lane * 8 + q * 512;
        u16x8 a8 = *reinterpret_cast<const u16x8*>(ps + m);
        u16x8 b8 = *reinterpret_cast<const u16x8*>(pe + m);
        float4 t0 = *reinterpret_cast<const float4*>(se + m);
        float4 t1 = *reinterpret_cast<const float4*>(se + m + 4);
        float4 u0 = make_float4(0.f, 0.f, 0.f, 0.f), u1 = u0;
        if (has_s) {
            u0 = *reinterpret_cast<const float4*>(ss + m);
            u1 = *reinterpret_cast<const float4*>(ss + m + 4);
        }
        float4 w0 = *reinterpret_cast<const float4*>(pw + m);
        float4 w1 = *reinterpret_cast<const float4*>(pw + m + 4);
        float4 v0 = *reinterpret_cast<const float4*>(mlp2_w + m);
        float4 v1 = *reinterpret_cast<const float4*>(mlp2_w + m + 4);
        float x;
        x = bf2f(a8[0]) + bf2f(b8[0]) + w0.x + (t0.x - u0.x) * inv; part += fmaxf(x, 0.f) * v0.x;
        x = bf2f(a8[1]) + bf2f(b8[1]) + w0.y + (t0.y - u0.y) * inv; part += fmaxf(x, 0.f) * v0.y;
        x = bf2f(a8[2]) + bf2f(b8[2]) + w0.z + (t0.z - u0.z) * inv; part += fmaxf(x, 0.f) * v0.z;
        x = bf2f(a8[3]) + bf2f(b8[3]) + w0.w + (t0.w - u0.w) * inv; part += fmaxf(x, 0.f) * v0.w;
        x = bf2f(a8[4]) + bf2f(b8[4]) + w1.x + (t1.x - u1.x) * inv; part += fmaxf(x, 0.f) * v1.x;
        x = bf2f(a8[5]) + bf2f(b8[5]) + w1.y + (t1.y - u1.y) * inv; part += fmaxf(x, 0.f) * v1.y;
        x = bf2f(a8[6]) + bf2f(b8[6]) + w1.z + (t1.z - u1.z) * inv; part += fmaxf(x, 0.f) * v1.z;
        x = bf2f(a8[7]) + bf2f(b8[7]) + w1.w + (t1.w - u1.w) * inv; part += fmaxf(x, 0.f) * v1.w;
    }
    #pragma unroll
    for (int off = 32; off > 0; off >>= 1) part += __shfl_down(part, off);
    if (lane == 0) out[c] = part + mlp2_b[0] + wscore[wi];
}

extern "C" void kernel_launch(void* const* d_in, const int* in_sizes, int n_in,
                              void* d_out, int out_size, void* d_ws, size_t ws_size,
                              hipStream_t stream) {
    const float* encoded_doc = (const float*)d_in[0];
    const int*   cand_starts = (const int*)d_in[1];
    const int*   cand_ends   = (const int*)d_in[2];
    const float* width_emb   = (const float*)d_in[3];
    const float* width_prior = (const float*)d_in[4];
    const float* attn_w      = (const float*)d_in[5];
    const float* attn_b      = (const float*)d_in[6];
    const float* mlp1_w      = (const float*)d_in[7];
    const float* mlp1_b      = (const float*)d_in[8];
    const float* mlp2_w      = (const float*)d_in[9];
    const float* mlp2_b      = (const float*)d_in[10];
    const float* wmlp1_w     = (const float*)d_in[11];
    const float* wmlp1_b     = (const float*)d_in[12];
    const float* wmlp2_w     = (const float*)d_in[13];
    const float* wmlp2_b     = (const float*)d_in[14];
    float* out = (float*)d_out;

    // workspace layout (float units from base; all large blocks 16B-aligned)
    float* Sbuf   = (float*)d_ws;                      // NW*1024
    float* T      = Sbuf + (size_t)NW * M;             // NCH*M = 65536
    float* PW     = T + NCH * M;                       // 30*1024
    float* ewa    = PW + MSW * M;                      // 4096
    float* Dpre   = ewa + NW;                          // 4160
    float* wscore = Dpre + 4160;                       // 64
    unsigned short* Pse  = (unsigned short*)(wscore + 64);      // NW*2048 bf16
    unsigned short* docb = Pse + (size_t)NW * 2048;             // NW*H bf16
    unsigned short* Btb  = docb + (size_t)NW * H;               // 3072*H bf16
    int* hist = (int*)(Btb + (size_t)3072 * H);        // 4096
    int* offs = hist + 4096;                           // 4096
    int* perm = offs + 4096;                           // NC

    k_doc_prep<<<NW / 4, 256, 0, stream>>>(encoded_doc, attn_w, attn_b, docb, ewa);
    k_cvt_bt<<<dim3(H / 32, M / 32, 3), 256, 0, stream>>>(mlp1_w, Btb);
    k_dscan<<<1, 256, 0, stream>>>(ewa, Dpre);
    k_pw<<<dim3(MSW, M / 256), 256, 0, stream>>>(width_emb, mlp1_w, mlp1_b, PW);
    k_wscore<<<MSW, 256, 0, stream>>>(width_prior, wmlp1_w, wmlp1_b, wmlp2_w, wmlp2_b, wscore);
    k_zero<<<NW / 256, 256, 0, stream>>>(hist);
    k_hist<<<NC / 256, 256, 0, stream>>>(cand_starts, hist);
    k_hscan<<<1, 256, 0, stream>>>(hist, offs);
    k_scatter<<<NC / 256, 256, 0, stream>>>(cand_starts, offs, perm);
    k_proj_mfma<<<768, 256, 0, stream>>>(docb, Btb, Pse, Sbuf);
    k_scan1<<<dim3(M / 256, NCH), 256, 0, stream>>>(Sbuf, ewa, T);
    k_scan2<<<M / 256, 256, 0, stream>>>(T);
    k_scan3<<<dim3(M / 256, NCH), 256, 0, stream>>>(Sbuf, ewa, T);
    k_cand<<<NC / 4, 256, 0, stream>>>(Pse, Sbuf, PW, Dpre, wscore, perm,
                                       cand_starts, cand_ends, mlp2_w, mlp2_b, out);
}

// Round 7
// 124.375 us; speedup vs baseline: 5.2646x; 1.0934x over previous
//
#include <hip/hip_runtime.h>
#include <math.h>

#define NW 4096
#define H 768
#define NC 49152
#define MSW 30
#define E 20
#define M 1024
#define CHUNK 64
#define NCH (NW / CHUNK)
#define NKT (H / 64)   // 12 K-tiles
// Pse: bf16 [NW][2048] (cols 0:1024 start-proj, 1024:2048 end-proj)
// Sbuf: f32 [NW][1024] attn-proj, overwritten in place by exp-weighted prefix:
//   Sbuf[r][m] = S[r+1][m] = sum_{i<=r} ewa[i]*Pattn[i][m]

typedef short bf16x8 __attribute__((ext_vector_type(8)));
typedef unsigned short u16x8 __attribute__((ext_vector_type(8)));
typedef float f32x4 __attribute__((ext_vector_type(4)));

__device__ __forceinline__ unsigned short f2bf(float x) {
    unsigned u = __float_as_uint(x);
    return (unsigned short)((u + 0x7fff + ((u >> 16) & 1)) >> 16);  // RNE
}
__device__ __forceinline__ float bf2f(unsigned short b) {
    return __uint_as_float(((unsigned)b) << 16);
}
__device__ __forceinline__ void gload16(const void* g, void* l) {
    __builtin_amdgcn_global_load_lds((const __attribute__((address_space(1))) void*)g,
                                     (__attribute__((address_space(3))) void*)l, 16, 0, 0);
}

// ---------------- fused: docb = bf16(doc); ewa = exp(doc @ attn_w + b) ----------------
__global__ __launch_bounds__(256) void k_doc_prep(const float* __restrict__ doc,
                                                  const float* __restrict__ attn_w,
                                                  const float* __restrict__ attn_b,
                                                  unsigned short* __restrict__ docb,
                                                  float* __restrict__ ewa) {
    int row = blockIdx.x * 4 + (threadIdx.x >> 6);
    int lane = threadIdx.x & 63;
    const float* r = doc + (size_t)row * H;
    float s = 0.f;
    #pragma unroll
    for (int q = 0; q < 3; ++q) {
        int idx = q * 256 + lane * 4;
        float4 v = *reinterpret_cast<const float4*>(r + idx);
        float4 w = *reinterpret_cast<const float4*>(attn_w + idx);
        s += v.x * w.x + v.y * w.y + v.z * w.z + v.w * w.w;
        ushort4 o;
        o.x = f2bf(v.x); o.y = f2bf(v.y); o.z = f2bf(v.z); o.w = f2bf(v.w);
        *reinterpret_cast<ushort4*>(docb + (size_t)row * H + idx) = o;
    }
    #pragma unroll
    for (int off = 32; off > 0; off >>= 1) s += __shfl_down(s, off);
    if (lane == 0) ewa[row] = expf(s + attn_b[0]);
}

// ---------------- Bt[col][k] = bf16(mlp1_w[rb(part)+k][m]), col = part*1024+m ----------------
__global__ __launch_bounds__(256) void k_cvt_bt(const float* __restrict__ mlp1_w,
                                                unsigned short* __restrict__ Bt) {
    __shared__ float sh[32][33];
    int k0 = blockIdx.x * 32, m0 = blockIdx.y * 32, part = blockIdx.z;
    int rb = part == 0 ? 0 : (part == 1 ? H : (2 * H + E));
    int tx = threadIdx.x & 31, ty = threadIdx.x >> 5;
    #pragma unroll
    for (int it = 0; it < 4; ++it) {
        int kk = ty + it * 8;
        sh[kk][tx] = mlp1_w[(size_t)(rb + k0 + kk) * M + m0 + tx];
    }
    __syncthreads();
    #pragma unroll
    for (int it = 0; it < 4; ++it) {
        int mm = ty + it * 8;
        Bt[(size_t)(part * M + m0 + mm) * H + k0 + tx] = f2bf(sh[tx][mm]);
    }
}

// ---------------- Dpre[i] = sum_{j<i} ewa[j] ----------------
__global__ __launch_bounds__(256) void k_dscan(const float* __restrict__ ewa,
                                               float* __restrict__ Dpre) {
    int t = threadIdx.x;
    float v[16];
    float sum = 0.f;
    #pragma unroll
    for (int i = 0; i < 16; ++i) { v[i] = ewa[t * 16 + i]; sum += v[i]; }
    __shared__ float sh[256];
    sh[t] = sum;
    __syncthreads();
    for (int off = 1; off < 256; off <<= 1) {
        float x = (t >= off) ? sh[t - off] : 0.f;
        __syncthreads();
        sh[t] += x;
        __syncthreads();
    }
    float run = sh[t] - sum;
    #pragma unroll
    for (int i = 0; i < 16; ++i) { run += v[i]; Dpre[t * 16 + i + 1] = run; }
    if (t == 0) Dpre[0] = 0.f;
}

// ---------------- PW[w][m] = width_emb[w] @ W1[2H:2H+E] + mlp1_b ----------------
__global__ __launch_bounds__(256) void k_pw(const float* __restrict__ width_emb,
                                            const float* __restrict__ mlp1_w,
                                            const float* __restrict__ mlp1_b,
                                            float* __restrict__ PW) {
    int w = blockIdx.x;
    int m = blockIdx.y * 256 + threadIdx.x;
    float acc = mlp1_b[m];
    #pragma unroll
    for (int e = 0; e < E; ++e)
        acc += width_emb[w * E + e] * mlp1_w[(size_t)(2 * H + e) * M + m];
    PW[w * M + m] = acc;
}

// ---------------- wscore[w] ----------------
__global__ __launch_bounds__(256) void k_wscore(const float* __restrict__ wp_emb,
                                                const float* __restrict__ w1,
                                                const float* __restrict__ b1,
                                                const float* __restrict__ w2,
                                                const float* __restrict__ b2,
                                                float* __restrict__ wscore) {
    int w = blockIdx.x;
    int tid = threadIdx.x;
    float part = 0.f;
    for (int m = tid; m < M; m += 256) {
        float h = b1[m];
        #pragma unroll
        for (int e = 0; e < E; ++e) h += wp_emb[w * E + e] * w1[e * M + m];
        part += fmaxf(h, 0.f) * w2[m];
    }
    __shared__ float red[256];
    red[tid] = part;
    __syncthreads();
    for (int s = 128; s > 0; s >>= 1) {
        if (tid < s) red[tid] += red[tid + s];
        __syncthreads();
    }
    if (tid == 0) wscore[w] = red[0] + b2[0];
}

// ---------------- sort-by-start: zero / hist / exclusive-scan / scatter ----------------
__global__ __launch_bounds__(256) void k_zero(int* __restrict__ hist) {
    hist[blockIdx.x * 256 + threadIdx.x] = 0;
}
__global__ __launch_bounds__(256) void k_hist(const int* __restrict__ starts,
                                              int* __restrict__ hist) {
    atomicAdd(&hist[starts[blockIdx.x * 256 + threadIdx.x]], 1);
}
__global__ __launch_bounds__(256) void k_hscan(const int* __restrict__ hist,
                                               int* __restrict__ offs) {
    int t = threadIdx.x;
    int v[16];
    int sum = 0;
    #pragma unroll
    for (int i = 0; i < 16; ++i) { v[i] = hist[t * 16 + i]; sum += v[i]; }
    __shared__ int sh[256];
    sh[t] = sum;
    __syncthreads();
    for (int off = 1; off < 256; off <<= 1) {
        int x = (t >= off) ? sh[t - off] : 0;
        __syncthreads();
        sh[t] += x;
        __syncthreads();
    }
    int run = sh[t] - sum;
    #pragma unroll
    for (int i = 0; i < 16; ++i) { offs[t * 16 + i] = run; run += v[i]; }
}
__global__ __launch_bounds__(256) void k_scatter(const int* __restrict__ starts,
                                                 int* __restrict__ offs,
                                                 int* __restrict__ perm) {
    int c = blockIdx.x * 256 + threadIdx.x;
    int p = atomicAdd(&offs[starts[c]], 1);
    perm[p] = c;
}

// ---------------- MFMA projection: 256x192 tile, 8 waves, 8x3 frags/wave ------------
// Fragment-ordered LDS (all ds_reads linear -> 0 bank conflicts), double-buffered,
// counted vmcnt(7) (7 gload16/thread/K-tile stay in flight across barriers),
// setprio around the 48-MFMA cluster. Grid 256 = 1 block/CU exactly.
__global__ __launch_bounds__(512, 2) void k_proj_mfma(const unsigned short* __restrict__ docb,
                                                      const unsigned short* __restrict__ Bt,
                                                      unsigned short* __restrict__ Pse,
                                                      float* __restrict__ Sbuf) {
    __shared__ unsigned short As[2][16384];  // [buf][mg:16][ks:2][g:4][ri:16][j:8] 64KB
    __shared__ unsigned short Bs[2][12288];  // [buf][cg:12][ks:2][g:4][ci:16][j:8] 48KB
    int tid = threadIdx.x;
    // XCD-bijective supertile map (256 blocks): each XCD owns 8 col-tiles x 4 row-tiles
    // -> footprint 2.36MB Bt + 1.57MB docb = 3.9MB < 4MB L2.
    int bid = blockIdx.x;
    int xcd = bid & 7, rr0 = bid >> 3;              // rr0: 0..31
    int coltile = (xcd & 1) * 8 + (rr0 & 7);        // 0..15
    int rowtile = (xcd >> 1) * 4 + (rr0 >> 3);      // 0..15
    int col0 = coltile * 192;
    int row0 = rowtile * 256;
    int wv = tid >> 6, lane = tid & 63;
    int wr = wv >> 2, wc = wv & 3;                  // 2M x 4N waves

    f32x4 acc[8][3];
    #pragma unroll
    for (int mi = 0; mi < 8; ++mi)
        #pragma unroll
        for (int ni = 0; ni < 3; ++ni) acc[mi][ni] = (f32x4){0.f, 0.f, 0.f, 0.f};

    // 7 gload16 per thread per K-tile (4 A + 3 B) -> vmcnt(7) == prev tile landed
    #define STAGE(buf, k0)                                                            \
        {                                                                             \
            _Pragma("unroll")                                                         \
            for (int i = 0; i < 4; ++i) {                                             \
                int s = i * 512 + tid;                                                \
                int mg = s >> 7, ks = (s >> 6) & 1, g = (s >> 4) & 3, ri = s & 15;    \
                gload16(docb + (size_t)(row0 + mg * 16 + ri) * H + (k0) + ks * 32 + g * 8, \
                        (char*)As[buf] + s * 16);                                     \
            }                                                                         \
            _Pragma("unroll")                                                         \
            for (int i = 0; i < 3; ++i) {                                             \
                int s = i * 512 + tid;                                                \
                int cg = s >> 7, ks = (s >> 6) & 1, g = (s >> 4) & 3, ci = s & 15;    \
                gload16(Bt + (size_t)(col0 + cg * 16 + ci) * H + (k0) + ks * 32 + g * 8, \
                        (char*)Bs[buf] + s * 16);                                     \
            }                                                                         \
        }

    STAGE(0, 0);
    STAGE(1, 64);
    asm volatile("s_waitcnt vmcnt(7)" ::: "memory");  // tile 0 landed (tile 1 in flight)
    __builtin_amdgcn_s_barrier();

    #pragma unroll 1
    for (int t = 0; t < NKT; ++t) {
        int cur = t & 1;
        bf16x8 af[2][8], bfr[2][3];
        #pragma unroll
        for (int ks = 0; ks < 2; ++ks) {
            #pragma unroll
            for (int mi = 0; mi < 8; ++mi)
                af[ks][mi] = *reinterpret_cast<const bf16x8*>(
                    (char*)As[cur] + (wr * 8 + mi) * 2048 + ks * 1024 + lane * 16);
            #pragma unroll
            for (int ni = 0; ni < 3; ++ni)
                bfr[ks][ni] = *reinterpret_cast<const bf16x8*>(
                    (char*)Bs[cur] + (wc * 3 + ni) * 2048 + ks * 1024 + lane * 16);
        }
        asm volatile("s_waitcnt lgkmcnt(0)" ::: "memory");  // own reads retired
        __builtin_amdgcn_s_barrier();                       // all waves done with buf[cur]
        if (t + 2 < NKT) STAGE(cur, (t + 2) * 64);          // overwrite buf[cur] w/ tile t+2
        __builtin_amdgcn_s_setprio(1);
        #pragma unroll
        for (int ks = 0; ks < 2; ++ks)
            #pragma unroll
            for (int mi = 0; mi < 8; ++mi)
                #pragma unroll
                for (int ni = 0; ni < 3; ++ni)
                    acc[mi][ni] = __builtin_amdgcn_mfma_f32_16x16x32_bf16(
                        af[ks][mi], bfr[ks][ni], acc[mi][ni], 0, 0, 0);
        __builtin_amdgcn_s_setprio(0);
        if (t + 2 < NKT) {
            asm volatile("s_waitcnt vmcnt(7)" ::: "memory");  // tile t+1 landed, t+2 in flight
            __builtin_amdgcn_s_barrier();
        } else if (t + 2 == NKT) {
            asm volatile("s_waitcnt vmcnt(0)" ::: "memory");  // drain: last tile landed
            __builtin_amdgcn_s_barrier();
        }
        // t == NKT-1: no further LDS use
    }
    #undef STAGE

    int cr = (lane >> 4) * 4;
    int cc = lane & 15;
    #pragma unroll
    for (int mi = 0; mi < 8; ++mi) {
        #pragma unroll
        for (int ni = 0; ni < 3; ++ni) {
            int rrow = row0 + wr * 128 + mi * 16 + cr;
            int cabs = col0 + wc * 48 + ni * 16 + cc;
            int part = cabs >> 10;
            int cm = cabs & 1023;
            if (part < 2) {
                unsigned short* dst = Pse + (size_t)rrow * 2048 + part * 1024 + cm;
                #pragma unroll
                for (int j = 0; j < 4; ++j) dst[(size_t)j * 2048] = f2bf(acc[mi][ni][j]);
            } else {
                float* dst = Sbuf + (size_t)rrow * M + cm;
                #pragma unroll
                for (int j = 0; j < 4; ++j) dst[(size_t)j * M] = acc[mi][ni][j];
            }
        }
    }
}

// ---------------- scan phase 1: per-chunk totals of ewa[i]*Pattn[i][m] ----------------
__global__ __launch_bounds__(256) void k_scan1(const float* __restrict__ Sbuf,
                                               const float* __restrict__ ewa,
                                               float* __restrict__ T) {
    int m = blockIdx.x * 256 + threadIdx.x;
    int c = blockIdx.y;
    __shared__ float ew[CHUNK];
    if (threadIdx.x < CHUNK) ew[threadIdx.x] = ewa[c * CHUNK + threadIdx.x];
    __syncthreads();
    const float* base = Sbuf + (size_t)(c * CHUNK) * M + m;
    float acc = 0.f;
    #pragma unroll 8
    for (int i = 0; i < CHUNK; ++i)
        acc += ew[i] * base[(size_t)i * M];
    T[c * M + m] = acc;
}

// ---------------- scan phase 2: exclusive scan of chunk totals (reg-resident) ----------------
__global__ __launch_bounds__(256) void k_scan2(float* __restrict__ T) {
    int m = blockIdx.x * 256 + threadIdx.x;
    float v[NCH];
    #pragma unroll
    for (int c = 0; c < NCH; ++c) v[c] = T[c * M + m];
    float run = 0.f;
    #pragma unroll
    for (int c = 0; c < NCH; ++c) { float t = v[c]; T[c * M + m] = run; run += t; }
}

// ---------------- scan phase 3: in-place inclusive prefix over Sbuf ----------------
__global__ __launch_bounds__(256) void k_scan3(float* __restrict__ Sbuf,
                                               const float* __restrict__ ewa,
                                               const float* __restrict__ T) {
    int m = blockIdx.x * 256 + threadIdx.x;
    int c = blockIdx.y;
    __shared__ float ew[CHUNK];
    if (threadIdx.x < CHUNK) ew[threadIdx.x] = ewa[c * CHUNK + threadIdx.x];
    __syncthreads();
    float acc = T[c * M + m];
    float* base = Sbuf + (size_t)(c * CHUNK) * M + m;
    #pragma unroll 4
    for (int i = 0; i < CHUNK; ++i) {
        float* p = base + (size_t)i * M;
        acc += ew[i] * (*p);
        *p = acc;
    }
}

// ---------------- per-candidate scoring (sorted order, XCD-swizzled) ----------------
__global__ __launch_bounds__(256) void k_cand(const unsigned short* __restrict__ Pse,
                                              const float* __restrict__ Sbuf,
                                              const float* __restrict__ PW,
                                              const float* __restrict__ Dpre,
                                              const float* __restrict__ wscore,
                                              const int* __restrict__ perm,
                                              const int* __restrict__ starts,
                                              const int* __restrict__ ends,
                                              const float* __restrict__ mlp2_w,
                                              const float* __restrict__ mlp2_b,
                                              float* __restrict__ out) {
    int bid = blockIdx.x;                                   // 12288 blocks, %8==0 -> bijective
    int eff = (bid & 7) * (12288 / 8) + (bid >> 3);         // XCD-contiguous sorted ranges
    int j = eff * 4 + (threadIdx.x >> 6);
    int lane = threadIdx.x & 63;
    int c = perm[j];
    int s = starts[c], e = ends[c];
    int wi = e - s;
    wi = wi < 0 ? 0 : (wi > MSW - 1 ? MSW - 1 : wi);

    float inv = 1.f / (Dpre[e + 1] - Dpre[s]);

    const unsigned short* ps = Pse + (size_t)s * 2048;
    const unsigned short* pe = Pse + (size_t)e * 2048 + 1024;
    const float* se = Sbuf + (size_t)e * M;                 // S[e+1]
    const float* ss = Sbuf + (size_t)(s > 0 ? s - 1 : 0) * M;  // S[s]
    const float* pw = PW + (size_t)wi * M;
    bool has_s = (s > 0);

    float part = 0.f;
    #pragma unroll
    for (int q = 0; q < 2; ++q) {
        int m = lane * 8 + q * 512;
        u16x8 a8 = *reinterpret_cast<const u16x8*>(ps + m);
        u16x8 b8 = *reinterpret_cast<const u16x8*>(pe + m);
        float4 t0 = *reinterpret_cast<const float4*>(se + m);
        float4 t1 = *reinterpret_cast<const float4*>(se + m + 4);
        float4 u0 = make_float4(0.f, 0.f, 0.f, 0.f), u1 = u0;
        if (has_s) {
            u0 = *reinterpret_cast<const float4*>(ss + m);
            u1 = *reinterpret_cast<const float4*>(ss + m + 4);
        }
        float4 w0 = *reinterpret_cast<const float4*>(pw + m);
        float4 w1 = *reinterpret_cast<const float4*>(pw + m + 4);
        float4 v0 = *reinterpret_cast<const float4*>(mlp2_w + m);
        float4 v1 = *reinterpret_cast<const float4*>(mlp2_w + m + 4);
        float x;
        x = bf2f(a8[0]) + bf2f(b8[0]) + w0.x + (t0.x - u0.x) * inv; part += fmaxf(x, 0.f) * v0.x;
        x = bf2f(a8[1]) + bf2f(b8[1]) + w0.y + (t0.y - u0.y) * inv; part += fmaxf(x, 0.f) * v0.y;
        x = bf2f(a8[2]) + bf2f(b8[2]) + w0.z + (t0.z - u0.z) * inv; part += fmaxf(x, 0.f) * v0.z;
        x = bf2f(a8[3]) + bf2f(b8[3]) + w0.w + (t0.w - u0.w) * inv; part += fmaxf(x, 0.f) * v0.w;
        x = bf2f(a8[4]) + bf2f(b8[4]) + w1.x + (t1.x - u1.x) * inv; part += fmaxf(x, 0.f) * v1.x;
        x = bf2f(a8[5]) + bf2f(b8[5]) + w1.y + (t1.y - u1.y) * inv; part += fmaxf(x, 0.f) * v1.y;
        x = bf2f(a8[6]) + bf2f(b8[6]) + w1.z + (t1.z - u1.z) * inv; part += fmaxf(x, 0.f) * v1.z;
        x = bf2f(a8[7]) + bf2f(b8[7]) + w1.w + (t1.w - u1.w) * inv; part += fmaxf(x, 0.f) * v1.w;
    }
    #pragma unroll
    for (int off = 32; off > 0; off >>= 1) part += __shfl_down(part, off);
    if (lane == 0) out[c] = part + mlp2_b[0] + wscore[wi];
}

extern "C" void kernel_launch(void* const* d_in, const int* in_sizes, int n_in,
                              void* d_out, int out_size, void* d_ws, size_t ws_size,
                              hipStream_t stream) {
    const float* encoded_doc = (const float*)d_in[0];
    const int*   cand_starts = (const int*)d_in[1];
    const int*   cand_ends   = (const int*)d_in[2];
    const float* width_emb   = (const float*)d_in[3];
    const float* width_prior = (const float*)d_in[4];
    const float* attn_w      = (const float*)d_in[5];
    const float* attn_b      = (const float*)d_in[6];
    const float* mlp1_w      = (const float*)d_in[7];
    const float* mlp1_b      = (const float*)d_in[8];
    const float* mlp2_w      = (const float*)d_in[9];
    const float* mlp2_b      = (const float*)d_in[10];
    const float* wmlp1_w     = (const float*)d_in[11];
    const float* wmlp1_b     = (const float*)d_in[12];
    const float* wmlp2_w     = (const float*)d_in[13];
    const float* wmlp2_b     = (const float*)d_in[14];
    float* out = (float*)d_out;

    // workspace layout (float units from base; all large blocks 16B-aligned)
    float* Sbuf   = (float*)d_ws;                      // NW*1024
    float* T      = Sbuf + (size_t)NW * M;             // NCH*M = 65536
    float* PW     = T + NCH * M;                       // 30*1024
    float* ewa    = PW + MSW * M;                      // 4096
    float* Dpre   = ewa + NW;                          // 4160
    float* wscore = Dpre + 4160;                       // 64
    unsigned short* Pse  = (unsigned short*)(wscore + 64);      // NW*2048 bf16
    unsigned short* docb = Pse + (size_t)NW * 2048;             // NW*H bf16
    unsigned short* Btb  = docb + (size_t)NW * H;               // 3072*H bf16
    int* hist = (int*)(Btb + (size_t)3072 * H);        // 4096
    int* offs = hist + 4096;                           // 4096
    int* perm = offs + 4096;                           // NC

    k_doc_prep<<<NW / 4, 256, 0, stream>>>(encoded_doc, attn_w, attn_b, docb, ewa);
    k_cvt_bt<<<dim3(H / 32, M / 32, 3), 256, 0, stream>>>(mlp1_w, Btb);
    k_dscan<<<1, 256, 0, stream>>>(ewa, Dpre);
    k_pw<<<dim3(MSW, M / 256), 256, 0, stream>>>(width_emb, mlp1_w, mlp1_b, PW);
    k_wscore<<<MSW, 256, 0, stream>>>(width_prior, wmlp1_w, wmlp1_b, wmlp2_w, wmlp2_b, wscore);
    k_zero<<<NW / 256, 256, 0, stream>>>(hist);
    k_hist<<<NC / 256, 256, 0, stream>>>(cand_starts, hist);
    k_hscan<<<1, 256, 0, stream>>>(hist, offs);
    k_scatter<<<NC / 256, 256, 0, stream>>>(cand_starts, offs, perm);
    k_proj_mfma<<<256, 512, 0, stream>>>(docb, Btb, Pse, Sbuf);
    k_scan1<<<dim3(M / 256, NCH), 256, 0, stream>>>(Sbuf, ewa, T);
    k_scan2<<<M / 256, 256, 0, stream>>>(T);
    k_scan3<<<dim3(M / 256, NCH), 256, 0, stream>>>(Sbuf, ewa, T);
    k_cand<<<NC / 4, 256, 0, stream>>>(Pse, Sbuf, PW, Dpre, wscore, perm,
                                       cand_starts, cand_ends, mlp2_w, mlp2_b, out);
}

// Round 8
// 120.389 us; speedup vs baseline: 5.4389x; 1.0331x over previous
//
#include <hip/hip_runtime.h>
#include <math.h>

#define NW 4096
#define H 768
#define NC 49152
#define MSW 30
#define E 20
#define M 1024
#define CHUNK 64
#define NCH (NW / CHUNK)
#define NKT (H / 64)   // 12 K-tiles
// Pse: bf16 [NW][2048] (cols 0:1024 start-proj, 1024:2048 end-proj)
// Sbuf: f32 [NW][1024] attn-proj, overwritten in place by exp-weighted prefix:
//   Sbuf[r][m] = S[r+1][m] = sum_{i<=r} ewa[i]*Pattn[i][m]

typedef short bf16x8 __attribute__((ext_vector_type(8)));
typedef unsigned short u16x8 __attribute__((ext_vector_type(8)));
typedef float f32x4 __attribute__((ext_vector_type(4)));

__device__ __forceinline__ unsigned short f2bf(float x) {
    unsigned u = __float_as_uint(x);
    return (unsigned short)((u + 0x7fff + ((u >> 16) & 1)) >> 16);  // RNE
}
__device__ __forceinline__ float bf2f(unsigned short b) {
    return __uint_as_float(((unsigned)b) << 16);
}
__device__ __forceinline__ void gload16(const void* g, void* l) {
    __builtin_amdgcn_global_load_lds((const __attribute__((address_space(1))) void*)g,
                                     (__attribute__((address_space(3))) void*)l, 16, 0, 0);
}

// ------- fused: docb = bf16(doc); ewa = exp(doc @ attn_w + b); zero hist -------
__global__ __launch_bounds__(256) void k_doc_prep(const float* __restrict__ doc,
                                                  const float* __restrict__ attn_w,
                                                  const float* __restrict__ attn_b,
                                                  unsigned short* __restrict__ docb,
                                                  float* __restrict__ ewa,
                                                  int* __restrict__ hist) {
    if (blockIdx.x < 16) hist[blockIdx.x * 256 + threadIdx.x] = 0;
    int row = blockIdx.x * 4 + (threadIdx.x >> 6);
    int lane = threadIdx.x & 63;
    const float* r = doc + (size_t)row * H;
    float s = 0.f;
    #pragma unroll
    for (int q = 0; q < 3; ++q) {
        int idx = q * 256 + lane * 4;
        float4 v = *reinterpret_cast<const float4*>(r + idx);
        float4 w = *reinterpret_cast<const float4*>(attn_w + idx);
        s += v.x * w.x + v.y * w.y + v.z * w.z + v.w * w.w;
        ushort4 o;
        o.x = f2bf(v.x); o.y = f2bf(v.y); o.z = f2bf(v.z); o.w = f2bf(v.w);
        *reinterpret_cast<ushort4*>(docb + (size_t)row * H + idx) = o;
    }
    #pragma unroll
    for (int off = 32; off > 0; off >>= 1) s += __shfl_down(s, off);
    if (lane == 0) ewa[row] = expf(s + attn_b[0]);
}

// ---------------- Bt[col][k] = bf16(mlp1_w[rb(part)+k][m]), col = part*1024+m ----------------
__global__ __launch_bounds__(256) void k_cvt_bt(const float* __restrict__ mlp1_w,
                                                unsigned short* __restrict__ Bt) {
    __shared__ float sh[32][33];
    int k0 = blockIdx.x * 32, m0 = blockIdx.y * 32, part = blockIdx.z;
    int rb = part == 0 ? 0 : (part == 1 ? H : (2 * H + E));
    int tx = threadIdx.x & 31, ty = threadIdx.x >> 5;
    #pragma unroll
    for (int it = 0; it < 4; ++it) {
        int kk = ty + it * 8;
        sh[kk][tx] = mlp1_w[(size_t)(rb + k0 + kk) * M + m0 + tx];
    }
    __syncthreads();
    #pragma unroll
    for (int it = 0; it < 4; ++it) {
        int mm = ty + it * 8;
        Bt[(size_t)(part * M + m0 + mm) * H + k0 + tx] = f2bf(sh[tx][mm]);
    }
}

// ------- merged single-block scans: block0 = Dpre from ewa; block1 = offs from hist -------
__global__ __launch_bounds__(256) void k_scans2(const float* __restrict__ ewa,
                                                float* __restrict__ Dpre,
                                                const int* __restrict__ hist,
                                                int* __restrict__ offs) {
    __shared__ float shf[256];
    __shared__ int shi[256];
    int t = threadIdx.x;
    if (blockIdx.x == 0) {
        float v[16];
        float sum = 0.f;
        #pragma unroll
        for (int i = 0; i < 16; ++i) { v[i] = ewa[t * 16 + i]; sum += v[i]; }
        shf[t] = sum;
        __syncthreads();
        for (int off = 1; off < 256; off <<= 1) {
            float x = (t >= off) ? shf[t - off] : 0.f;
            __syncthreads();
            shf[t] += x;
            __syncthreads();
        }
        float run = shf[t] - sum;
        #pragma unroll
        for (int i = 0; i < 16; ++i) { run += v[i]; Dpre[t * 16 + i + 1] = run; }
        if (t == 0) Dpre[0] = 0.f;
    } else {
        int v[16];
        int sum = 0;
        #pragma unroll
        for (int i = 0; i < 16; ++i) { v[i] = hist[t * 16 + i]; sum += v[i]; }
        shi[t] = sum;
        __syncthreads();
        for (int off = 1; off < 256; off <<= 1) {
            int x = (t >= off) ? shi[t - off] : 0;
            __syncthreads();
            shi[t] += x;
            __syncthreads();
        }
        int run = shi[t] - sum;
        #pragma unroll
        for (int i = 0; i < 16; ++i) { offs[t * 16 + i] = run; run += v[i]; }
    }
}

// ------- merged PW + wscore: grid (MSW, 5); y<4 -> PW quarter, y==4 -> wscore -------
__global__ __launch_bounds__(256) void k_pw_ws(const float* __restrict__ width_emb,
                                               const float* __restrict__ mlp1_w,
                                               const float* __restrict__ mlp1_b,
                                               float* __restrict__ PW,
                                               const float* __restrict__ wp_emb,
                                               const float* __restrict__ w1,
                                               const float* __restrict__ b1,
                                               const float* __restrict__ w2,
                                               const float* __restrict__ b2,
                                               float* __restrict__ wscore) {
    __shared__ float red[256];
    int w = blockIdx.x;
    int y = blockIdx.y;
    int tid = threadIdx.x;
    if (y < 4) {
        int m = y * 256 + tid;
        float acc = mlp1_b[m];
        #pragma unroll
        for (int e = 0; e < E; ++e)
            acc += width_emb[w * E + e] * mlp1_w[(size_t)(2 * H + e) * M + m];
        PW[w * M + m] = acc;
    } else {
        float part = 0.f;
        for (int m = tid; m < M; m += 256) {
            float h = b1[m];
            #pragma unroll
            for (int e = 0; e < E; ++e) h += wp_emb[w * E + e] * w1[e * M + m];
            part += fmaxf(h, 0.f) * w2[m];
        }
        red[tid] = part;
        __syncthreads();
        for (int s = 128; s > 0; s >>= 1) {
            if (tid < s) red[tid] += red[tid + s];
            __syncthreads();
        }
        if (tid == 0) wscore[w] = red[0] + b2[0];
    }
}

// ---------------- sort-by-start: hist / scatter ----------------
__global__ __launch_bounds__(256) void k_hist(const int* __restrict__ starts,
                                              int* __restrict__ hist) {
    atomicAdd(&hist[starts[blockIdx.x * 256 + threadIdx.x]], 1);
}
__global__ __launch_bounds__(256) void k_scatter(const int* __restrict__ starts,
                                                 int* __restrict__ offs,
                                                 int* __restrict__ perm) {
    int c = blockIdx.x * 256 + threadIdx.x;
    int p = atomicAdd(&offs[starts[c]], 1);
    perm[p] = c;
}

// ---------------- MFMA projection: 256x192 tile, 8 waves, 8x3 frags/wave ------------
// Fragment-ordered LDS (linear ds_reads, 0 bank conflicts), double-buffered,
// counted vmcnt(7). KEY CHANGE vs r7: ds_read -> MFMA with COMPILER-scheduled
// counted lgkm interleave (no serializing inline lgkm before the cluster); the
// WAR fence (lgkm0 + sched_barrier + s_barrier) moves AFTER the MFMA cluster.
__global__ __launch_bounds__(512, 2) void k_proj_mfma(const unsigned short* __restrict__ docb,
                                                      const unsigned short* __restrict__ Bt,
                                                      unsigned short* __restrict__ Pse,
                                                      float* __restrict__ Sbuf) {
    __shared__ unsigned short As[2][16384];  // [buf][mg:16][ks:2][g:4][ri:16][j:8] 64KB
    __shared__ unsigned short Bs[2][12288];  // [buf][cg:12][ks:2][g:4][ci:16][j:8] 48KB
    int tid = threadIdx.x;
    // XCD-bijective supertile map (256 blocks): each XCD owns 8 col-tiles x 4 row-tiles
    int bid = blockIdx.x;
    int xcd = bid & 7, rr0 = bid >> 3;
    int coltile = (xcd & 1) * 8 + (rr0 & 7);
    int rowtile = (xcd >> 1) * 4 + (rr0 >> 3);
    int col0 = coltile * 192;
    int row0 = rowtile * 256;
    int wv = tid >> 6, lane = tid & 63;
    int wr = wv >> 2, wc = wv & 3;

    f32x4 acc[8][3];
    #pragma unroll
    for (int mi = 0; mi < 8; ++mi)
        #pragma unroll
        for (int ni = 0; ni < 3; ++ni) acc[mi][ni] = (f32x4){0.f, 0.f, 0.f, 0.f};

    // 7 gload16 per thread per K-tile (4 A + 3 B) -> vmcnt(7) == prev tile landed
    #define STAGE(buf, k0)                                                            \
        {                                                                             \
            _Pragma("unroll")                                                         \
            for (int i = 0; i < 4; ++i) {                                             \
                int s = i * 512 + tid;                                                \
                int mg = s >> 7, ks = (s >> 6) & 1, g = (s >> 4) & 3, ri = s & 15;    \
                gload16(docb + (size_t)(row0 + mg * 16 + ri) * H + (k0) + ks * 32 + g * 8, \
                        (char*)As[buf] + s * 16);                                     \
            }                                                                         \
            _Pragma("unroll")                                                         \
            for (int i = 0; i < 3; ++i) {                                             \
                int s = i * 512 + tid;                                                \
                int cg = s >> 7, ks = (s >> 6) & 1, g = (s >> 4) & 3, ci = s & 15;    \
                gload16(Bt + (size_t)(col0 + cg * 16 + ci) * H + (k0) + ks * 32 + g * 8, \
                        (char*)Bs[buf] + s * 16);                                     \
            }                                                                         \
        }

    STAGE(0, 0);
    STAGE(1, 64);
    asm volatile("s_waitcnt vmcnt(7)" ::: "memory");  // tile 0 landed (tile 1 in flight)
    __builtin_amdgcn_s_barrier();

    #pragma unroll 1
    for (int t = 0; t < NKT; ++t) {
        int cur = t & 1;
        bf16x8 af[2][8], bfr[2][3];
        #pragma unroll
        for (int ks = 0; ks < 2; ++ks) {
            #pragma unroll
            for (int mi = 0; mi < 8; ++mi)
                af[ks][mi] = *reinterpret_cast<const bf16x8*>(
                    (char*)As[cur] + (wr * 8 + mi) * 2048 + ks * 1024 + lane * 16);
            #pragma unroll
            for (int ni = 0; ni < 3; ++ni)
                bfr[ks][ni] = *reinterpret_cast<const bf16x8*>(
                    (char*)Bs[cur] + (wc * 3 + ni) * 2048 + ks * 1024 + lane * 16);
        }
        // MFMA cluster directly after the reads: compiler interleaves counted
        // lgkmcnt waits so early MFMAs overlap the tail ds_reads.
        __builtin_amdgcn_s_setprio(1);
        #pragma unroll
        for (int ks = 0; ks < 2; ++ks)
            #pragma unroll
            for (int mi = 0; mi < 8; ++mi)
                #pragma unroll
                for (int ni = 0; ni < 3; ++ni)
                    acc[mi][ni] = __builtin_amdgcn_mfma_f32_16x16x32_bf16(
                        af[ks][mi], bfr[ks][ni], acc[mi][ni], 0, 0, 0);
        __builtin_amdgcn_s_setprio(0);
        if (t + 2 < NKT) {
            asm volatile("s_waitcnt lgkmcnt(0)" ::: "memory");  // all buf[cur] reads retired
            __builtin_amdgcn_sched_barrier(0);                  // pin reads/MFMAs above fence
            __builtin_amdgcn_s_barrier();                       // chip-wide: buf[cur] free
            STAGE(cur, (t + 2) * 64);                           // overwrite buf[cur] w/ t+2
            asm volatile("s_waitcnt vmcnt(7)" ::: "memory");    // tile t+1 landed
            __builtin_amdgcn_s_barrier();                       // buf[cur^1] ready
        } else if (t + 2 == NKT) {
            asm volatile("s_waitcnt vmcnt(0)" ::: "memory");    // drain last tile
            __builtin_amdgcn_s_barrier();
        }
        // t == NKT-1: no further LDS use
    }
    #undef STAGE

    int cr = (lane >> 4) * 4;
    int cc = lane & 15;
    #pragma unroll
    for (int mi = 0; mi < 8; ++mi) {
        #pragma unroll
        for (int ni = 0; ni < 3; ++ni) {
            int rrow = row0 + wr * 128 + mi * 16 + cr;
            int cabs = col0 + wc * 48 + ni * 16 + cc;
            int part = cabs >> 10;
            int cm = cabs & 1023;
            if (part < 2) {
                unsigned short* dst = Pse + (size_t)rrow * 2048 + part * 1024 + cm;
                #pragma unroll
                for (int j = 0; j < 4; ++j) dst[(size_t)j * 2048] = f2bf(acc[mi][ni][j]);
            } else {
                float* dst = Sbuf + (size_t)rrow * M + cm;
                #pragma unroll
                for (int j = 0; j < 4; ++j) dst[(size_t)j * M] = acc[mi][ni][j];
            }
        }
    }
}

// ---------------- scan phase 1: per-chunk totals of ewa[i]*Pattn[i][m] ----------------
__global__ __launch_bounds__(256) void k_scan1(const float* __restrict__ Sbuf,
                                               const float* __restrict__ ewa,
                                               float* __restrict__ T) {
    int m = blockIdx.x * 256 + threadIdx.x;
    int c = blockIdx.y;
    __shared__ float ew[CHUNK];
    if (threadIdx.x < CHUNK) ew[threadIdx.x] = ewa[c * CHUNK + threadIdx.x];
    __syncthreads();
    const float* base = Sbuf + (size_t)(c * CHUNK) * M + m;
    float acc = 0.f;
    #pragma unroll 8
    for (int i = 0; i < CHUNK; ++i)
        acc += ew[i] * base[(size_t)i * M];
    T[c * M + m] = acc;
}

// ---------------- scan phase 2: exclusive scan of chunk totals (reg-resident) ----------------
__global__ __launch_bounds__(256) void k_scan2(float* __restrict__ T) {
    int m = blockIdx.x * 256 + threadIdx.x;
    float v[NCH];
    #pragma unroll
    for (int c = 0; c < NCH; ++c) v[c] = T[c * M + m];
    float run = 0.f;
    #pragma unroll
    for (int c = 0; c < NCH; ++c) { float t = v[c]; T[c * M + m] = run; run += t; }
}

// ---------------- scan phase 3: in-place inclusive prefix over Sbuf ----------------
__global__ __launch_bounds__(256) void k_scan3(float* __restrict__ Sbuf,
                                               const float* __restrict__ ewa,
                                               const float* __restrict__ T) {
    int m = blockIdx.x * 256 + threadIdx.x;
    int c = blockIdx.y;
    __shared__ float ew[CHUNK];
    if (threadIdx.x < CHUNK) ew[threadIdx.x] = ewa[c * CHUNK + threadIdx.x];
    __syncthreads();
    float acc = T[c * M + m];
    float* base = Sbuf + (size_t)(c * CHUNK) * M + m;
    #pragma unroll 4
    for (int i = 0; i < CHUNK; ++i) {
        float* p = base + (size_t)i * M;
        acc += ew[i] * (*p);
        *p = acc;
    }
}

// ---------------- per-candidate scoring (sorted order, XCD-swizzled) ----------------
__global__ __launch_bounds__(256) void k_cand(const unsigned short* __restrict__ Pse,
                                              const float* __restrict__ Sbuf,
                                              const float* __restrict__ PW,
                                              const float* __restrict__ Dpre,
                                              const float* __restrict__ wscore,
                                              const int* __restrict__ perm,
                                              const int* __restrict__ starts,
                                              const int* __restrict__ ends,
                                              const float* __restrict__ mlp2_w,
                                              const float* __restrict__ mlp2_b,
                                              float* __restrict__ out) {
    int bid = blockIdx.x;                                   // 12288 blocks, %8==0 -> bijective
    int eff = (bid & 7) * (12288 / 8) + (bid >> 3);         // XCD-contiguous sorted ranges
    int j = eff * 4 + (threadIdx.x >> 6);
    int lane = threadIdx.x & 63;
    int c = perm[j];
    int s = starts[c], e = ends[c];
    int wi = e - s;
    wi = wi < 0 ? 0 : (wi > MSW - 1 ? MSW - 1 : wi);

    float inv = 1.f / (Dpre[e + 1] - Dpre[s]);

    const unsigned short* ps = Pse + (size_t)s * 2048;
    const unsigned short* pe = Pse + (size_t)e * 2048 + 1024;
    const float* se = Sbuf + (size_t)e * M;                 // S[e+1]
    const float* ss = Sbuf + (size_t)(s > 0 ? s - 1 : 0) * M;  // S[s]
    const float* pw = PW + (size_t)wi * M;
    bool has_s = (s > 0);

    float part = 0.f;
    #pragma unroll
    for (int q = 0; q < 2; ++q) {
        int m = lane * 8 + q * 512;
        u16x8 a8 = *reinterpret_cast<const u16x8*>(ps + m);
        u16x8 b8 = *reinterpret_cast<const u16x8*>(pe + m);
        float4 t0 = *reinterpret_cast<const float4*>(se + m);
        float4 t1 = *reinterpret_cast<const float4*>(se + m + 4);
        float4 u0 = make_float4(0.f, 0.f, 0.f, 0.f), u1 = u0;
        if (has_s) {
            u0 = *reinterpret_cast<const float4*>(ss + m);
            u1 = *reinterpret_cast<const float4*>(ss + m + 4);
        }
        float4 w0 = *reinterpret_cast<const float4*>(pw + m);
        float4 w1 = *reinterpret_cast<const float4*>(pw + m + 4);
        float4 v0 = *reinterpret_cast<const float4*>(mlp2_w + m);
        float4 v1 = *reinterpret_cast<const float4*>(mlp2_w + m + 4);
        float x;
        x = bf2f(a8[0]) + bf2f(b8[0]) + w0.x + (t0.x - u0.x) * inv; part += fmaxf(x, 0.f) * v0.x;
        x = bf2f(a8[1]) + bf2f(b8[1]) + w0.y + (t0.y - u0.y) * inv; part += fmaxf(x, 0.f) * v0.y;
        x = bf2f(a8[2]) + bf2f(b8[2]) + w0.z + (t0.z - u0.z) * inv; part += fmaxf(x, 0.f) * v0.z;
        x = bf2f(a8[3]) + bf2f(b8[3]) + w0.w + (t0.w - u0.w) * inv; part += fmaxf(x, 0.f) * v0.w;
        x = bf2f(a8[4]) + bf2f(b8[4]) + w1.x + (t1.x - u1.x) * inv; part += fmaxf(x, 0.f) * v1.x;
        x = bf2f(a8[5]) + bf2f(b8[5]) + w1.y + (t1.y - u1.y) * inv; part += fmaxf(x, 0.f) * v1.y;
        x = bf2f(a8[6]) + bf2f(b8[6]) + w1.z + (t1.z - u1.z) * inv; part += fmaxf(x, 0.f) * v1.z;
        x = bf2f(a8[7]) + bf2f(b8[7]) + w1.w + (t1.w - u1.w) * inv; part += fmaxf(x, 0.f) * v1.w;
    }
    #pragma unroll
    for (int off = 32; off > 0; off >>= 1) part += __shfl_down(part, off);
    if (lane == 0) out[c] = part + mlp2_b[0] + wscore[wi];
}

extern "C" void kernel_launch(void* const* d_in, const int* in_sizes, int n_in,
                              void* d_out, int out_size, void* d_ws, size_t ws_size,
                              hipStream_t stream) {
    const float* encoded_doc = (const float*)d_in[0];
    const int*   cand_starts = (const int*)d_in[1];
    const int*   cand_ends   = (const int*)d_in[2];
    const float* width_emb   = (const float*)d_in[3];
    const float* width_prior = (const float*)d_in[4];
    const float* attn_w      = (const float*)d_in[5];
    const float* attn_b      = (const float*)d_in[6];
    const float* mlp1_w      = (const float*)d_in[7];
    const float* mlp1_b      = (const float*)d_in[8];
    const float* mlp2_w      = (const float*)d_in[9];
    const float* mlp2_b      = (const float*)d_in[10];
    const float* wmlp1_w     = (const float*)d_in[11];
    const float* wmlp1_b     = (const float*)d_in[12];
    const float* wmlp2_w     = (const float*)d_in[13];
    const float* wmlp2_b     = (const float*)d_in[14];
    float* out = (float*)d_out;

    // workspace layout (float units from base; all large blocks 16B-aligned)
    float* Sbuf   = (float*)d_ws;                      // NW*1024
    float* T      = Sbuf + (size_t)NW * M;             // NCH*M = 65536
    float* PW     = T + NCH * M;                       // 30*1024
    float* ewa    = PW + MSW * M;                      // 4096
    float* Dpre   = ewa + NW;                          // 4160
    float* wscore = Dpre + 4160;                       // 64
    unsigned short* Pse  = (unsigned short*)(wscore + 64);      // NW*2048 bf16
    unsigned short* docb = Pse + (size_t)NW * 2048;             // NW*H bf16
    unsigned short* Btb  = docb + (size_t)NW * H;               // 3072*H bf16
    int* hist = (int*)(Btb + (size_t)3072 * H);        // 4096
    int* offs = hist + 4096;                           // 4096
    int* perm = offs + 4096;                           // NC

    k_doc_prep<<<NW / 4, 256, 0, stream>>>(encoded_doc, attn_w, attn_b, docb, ewa, hist);
    k_cvt_bt<<<dim3(H / 32, M / 32, 3), 256, 0, stream>>>(mlp1_w, Btb);
    k_hist<<<NC / 256, 256, 0, stream>>>(cand_starts, hist);
    k_scans2<<<2, 256, 0, stream>>>(ewa, Dpre, hist, offs);
    k_pw_ws<<<dim3(MSW, 5), 256, 0, stream>>>(width_emb, mlp1_w, mlp1_b, PW,
                                              width_prior, wmlp1_w, wmlp1_b,
                                              wmlp2_w, wmlp2_b, wscore);
    k_scatter<<<NC / 256, 256, 0, stream>>>(cand_starts, offs, perm);
    k_proj_mfma<<<256, 512, 0, stream>>>(docb, Btb, Pse, Sbuf);
    k_scan1<<<dim3(M / 256, NCH), 256, 0, stream>>>(Sbuf, ewa, T);
    k_scan2<<<M / 256, 256, 0, stream>>>(T);
    k_scan3<<<dim3(M / 256, NCH), 256, 0, stream>>>(Sbuf, ewa, T);
    k_cand<<<NC / 4, 256, 0, stream>>>(Pse, Sbuf, PW, Dpre, wscore, perm,
                                       cand_starts, cand_ends, mlp2_w, mlp2_b, out);
}

// Round 9
// 116.158 us; speedup vs baseline: 5.6370x; 1.0364x over previous
//
#include <hip/hip_runtime.h>
#include <math.h>

#define NW 4096
#define H 768
#define NC 49152
#define MSW 30
#define E 20
#define M 1024
#define CHUNK 64
#define NCH (NW / CHUNK)
#define NKT (H / 64)   // 12 K-tiles
// Pse: bf16 [NW][2048] (cols 0:1024 start-proj, 1024:2048 end-proj)
// Sbuf: f32 [NW][1024] attn-proj, overwritten in place by exp-weighted prefix:
//   Sbuf[r][m] = S[r+1][m] = sum_{i<=r} ewa[i]*Pattn[i][m]

typedef short bf16x8 __attribute__((ext_vector_type(8)));
typedef unsigned short u16x8 __attribute__((ext_vector_type(8)));
typedef float f32x4 __attribute__((ext_vector_type(4)));

__device__ __forceinline__ unsigned short f2bf(float x) {
    unsigned u = __float_as_uint(x);
    return (unsigned short)((u + 0x7fff + ((u >> 16) & 1)) >> 16);  // RNE
}
__device__ __forceinline__ float bf2f(unsigned short b) {
    return __uint_as_float(((unsigned)b) << 16);
}
__device__ __forceinline__ void gload16(const void* g, void* l) {
    __builtin_amdgcn_global_load_lds((const __attribute__((address_space(1))) void*)g,
                                     (__attribute__((address_space(3))) void*)l, 16, 0, 0);
}

// ------- fused: docb = bf16(doc); ewa = exp(doc @ attn_w + b); zero hist -------
__global__ __launch_bounds__(256) void k_doc_prep(const float* __restrict__ doc,
                                                  const float* __restrict__ attn_w,
                                                  const float* __restrict__ attn_b,
                                                  unsigned short* __restrict__ docb,
                                                  float* __restrict__ ewa,
                                                  int* __restrict__ hist) {
    if (blockIdx.x < 16) hist[blockIdx.x * 256 + threadIdx.x] = 0;
    int row = blockIdx.x * 4 + (threadIdx.x >> 6);
    int lane = threadIdx.x & 63;
    const float* r = doc + (size_t)row * H;
    float s = 0.f;
    #pragma unroll
    for (int q = 0; q < 3; ++q) {
        int idx = q * 256 + lane * 4;
        float4 v = *reinterpret_cast<const float4*>(r + idx);
        float4 w = *reinterpret_cast<const float4*>(attn_w + idx);
        s += v.x * w.x + v.y * w.y + v.z * w.z + v.w * w.w;
        ushort4 o;
        o.x = f2bf(v.x); o.y = f2bf(v.y); o.z = f2bf(v.z); o.w = f2bf(v.w);
        *reinterpret_cast<ushort4*>(docb + (size_t)row * H + idx) = o;
    }
    #pragma unroll
    for (int off = 32; off > 0; off >>= 1) s += __shfl_down(s, off);
    if (lane == 0) ewa[row] = expf(s + attn_b[0]);
}

// ---------------- Bt[col][k] = bf16(mlp1_w[rb(part)+k][m]), col = part*1024+m ----------------
__global__ __launch_bounds__(256) void k_cvt_bt(const float* __restrict__ mlp1_w,
                                                unsigned short* __restrict__ Bt) {
    __shared__ float sh[32][33];
    int k0 = blockIdx.x * 32, m0 = blockIdx.y * 32, part = blockIdx.z;
    int rb = part == 0 ? 0 : (part == 1 ? H : (2 * H + E));
    int tx = threadIdx.x & 31, ty = threadIdx.x >> 5;
    #pragma unroll
    for (int it = 0; it < 4; ++it) {
        int kk = ty + it * 8;
        sh[kk][tx] = mlp1_w[(size_t)(rb + k0 + kk) * M + m0 + tx];
    }
    __syncthreads();
    #pragma unroll
    for (int it = 0; it < 4; ++it) {
        int mm = ty + it * 8;
        Bt[(size_t)(part * M + m0 + mm) * H + k0 + tx] = f2bf(sh[tx][mm]);
    }
}

// ------- merged scans: block0 = Dpre from ewa; block1 = offs+begs from hist -------
__global__ __launch_bounds__(256) void k_scans2(const float* __restrict__ ewa,
                                                float* __restrict__ Dpre,
                                                const int* __restrict__ hist,
                                                int* __restrict__ offs,
                                                int* __restrict__ begs) {
    __shared__ float shf[256];
    __shared__ int shi[256];
    int t = threadIdx.x;
    if (blockIdx.x == 0) {
        float v[16];
        float sum = 0.f;
        #pragma unroll
        for (int i = 0; i < 16; ++i) { v[i] = ewa[t * 16 + i]; sum += v[i]; }
        shf[t] = sum;
        __syncthreads();
        for (int off = 1; off < 256; off <<= 1) {
            float x = (t >= off) ? shf[t - off] : 0.f;
            __syncthreads();
            shf[t] += x;
            __syncthreads();
        }
        float run = shf[t] - sum;
        #pragma unroll
        for (int i = 0; i < 16; ++i) { run += v[i]; Dpre[t * 16 + i + 1] = run; }
        if (t == 0) Dpre[0] = 0.f;
    } else {
        int v[16];
        int sum = 0;
        #pragma unroll
        for (int i = 0; i < 16; ++i) { v[i] = hist[t * 16 + i]; sum += v[i]; }
        shi[t] = sum;
        __syncthreads();
        for (int off = 1; off < 256; off <<= 1) {
            int x = (t >= off) ? shi[t - off] : 0;
            __syncthreads();
            shi[t] += x;
            __syncthreads();
        }
        int run = shi[t] - sum;
        #pragma unroll
        for (int i = 0; i < 16; ++i) {
            offs[t * 16 + i] = run;
            begs[t * 16 + i] = run;
            run += v[i];
        }
        if (t == 255) begs[4096] = run;   // == NC
    }
}

// ------- merged PW + wscore: grid (MSW, 5); y<4 -> PW quarter, y==4 -> wscore -------
__global__ __launch_bounds__(256) void k_pw_ws(const float* __restrict__ width_emb,
                                               const float* __restrict__ mlp1_w,
                                               const float* __restrict__ mlp1_b,
                                               float* __restrict__ PW,
                                               const float* __restrict__ wp_emb,
                                               const float* __restrict__ w1,
                                               const float* __restrict__ b1,
                                               const float* __restrict__ w2,
                                               const float* __restrict__ b2,
                                               float* __restrict__ wscore) {
    __shared__ float red[256];
    int w = blockIdx.x;
    int y = blockIdx.y;
    int tid = threadIdx.x;
    if (y < 4) {
        int m = y * 256 + tid;
        float acc = mlp1_b[m];
        #pragma unroll
        for (int e = 0; e < E; ++e)
            acc += width_emb[w * E + e] * mlp1_w[(size_t)(2 * H + e) * M + m];
        PW[w * M + m] = acc;
    } else {
        float part = 0.f;
        for (int m = tid; m < M; m += 256) {
            float h = b1[m];
            #pragma unroll
            for (int e = 0; e < E; ++e) h += wp_emb[w * E + e] * w1[e * M + m];
            part += fmaxf(h, 0.f) * w2[m];
        }
        red[tid] = part;
        __syncthreads();
        for (int s = 128; s > 0; s >>= 1) {
            if (tid < s) red[tid] += red[tid + s];
            __syncthreads();
        }
        if (tid == 0) wscore[w] = red[0] + b2[0];
    }
}

// ---------------- sort-by-start: hist / scatter ----------------
__global__ __launch_bounds__(256) void k_hist(const int* __restrict__ starts,
                                              int* __restrict__ hist) {
    atomicAdd(&hist[starts[blockIdx.x * 256 + threadIdx.x]], 1);
}
__global__ __launch_bounds__(256) void k_scatter(const int* __restrict__ starts,
                                                 int* __restrict__ offs,
                                                 int* __restrict__ perm) {
    int c = blockIdx.x * 256 + threadIdx.x;
    int p = atomicAdd(&offs[starts[c]], 1);
    perm[p] = c;
}

// ---------------- MFMA projection: 256x192 tile, 8 waves; epilogue also emits
// chunk totals T[c][m] = sum_{r in chunk} ewa[r]*Pattn[r][m] (replaces k_scan1).
__global__ __launch_bounds__(512, 2) void k_proj_mfma(const unsigned short* __restrict__ docb,
                                                      const unsigned short* __restrict__ Bt,
                                                      const float* __restrict__ ewa,
                                                      unsigned short* __restrict__ Pse,
                                                      float* __restrict__ Sbuf,
                                                      float* __restrict__ T) {
    __shared__ unsigned short As[2][16384];  // [buf][mg:16][ks:2][g:4][ri:16][j:8] 64KB
    __shared__ unsigned short Bs[2][12288];  // [buf][cg:12][ks:2][g:4][ci:16][j:8] 48KB
    int tid = threadIdx.x;
    int bid = blockIdx.x;
    int xcd = bid & 7, rr0 = bid >> 3;
    int coltile = (xcd & 1) * 8 + (rr0 & 7);
    int rowtile = (xcd >> 1) * 4 + (rr0 >> 3);
    int col0 = coltile * 192;
    int row0 = rowtile * 256;
    int wv = tid >> 6, lane = tid & 63;
    int wr = wv >> 2, wc = wv & 3;

    f32x4 acc[8][3];
    #pragma unroll
    for (int mi = 0; mi < 8; ++mi)
        #pragma unroll
        for (int ni = 0; ni < 3; ++ni) acc[mi][ni] = (f32x4){0.f, 0.f, 0.f, 0.f};

    #define STAGE(buf, k0)                                                            \
        {                                                                             \
            _Pragma("unroll")                                                         \
            for (int i = 0; i < 4; ++i) {                                             \
                int s = i * 512 + tid;                                                \
                int mg = s >> 7, ks = (s >> 6) & 1, g = (s >> 4) & 3, ri = s & 15;    \
                gload16(docb + (size_t)(row0 + mg * 16 + ri) * H + (k0) + ks * 32 + g * 8, \
                        (char*)As[buf] + s * 16);                                     \
            }                                                                         \
            _Pragma("unroll")                                                         \
            for (int i = 0; i < 3; ++i) {                                             \
                int s = i * 512 + tid;                                                \
                int cg = s >> 7, ks = (s >> 6) & 1, g = (s >> 4) & 3, ci = s & 15;    \
                gload16(Bt + (size_t)(col0 + cg * 16 + ci) * H + (k0) + ks * 32 + g * 8, \
                        (char*)Bs[buf] + s * 16);                                     \
            }                                                                         \
        }

    STAGE(0, 0);
    STAGE(1, 64);
    asm volatile("s_waitcnt vmcnt(7)" ::: "memory");
    __builtin_amdgcn_s_barrier();

    #pragma unroll 1
    for (int t = 0; t < NKT; ++t) {
        int cur = t & 1;
        bf16x8 af[2][8], bfr[2][3];
        #pragma unroll
        for (int ks = 0; ks < 2; ++ks) {
            #pragma unroll
            for (int mi = 0; mi < 8; ++mi)
                af[ks][mi] = *reinterpret_cast<const bf16x8*>(
                    (char*)As[cur] + (wr * 8 + mi) * 2048 + ks * 1024 + lane * 16);
            #pragma unroll
            for (int ni = 0; ni < 3; ++ni)
                bfr[ks][ni] = *reinterpret_cast<const bf16x8*>(
                    (char*)Bs[cur] + (wc * 3 + ni) * 2048 + ks * 1024 + lane * 16);
        }
        __builtin_amdgcn_s_setprio(1);
        #pragma unroll
        for (int ks = 0; ks < 2; ++ks)
            #pragma unroll
            for (int mi = 0; mi < 8; ++mi)
                #pragma unroll
                for (int ni = 0; ni < 3; ++ni)
                    acc[mi][ni] = __builtin_amdgcn_mfma_f32_16x16x32_bf16(
                        af[ks][mi], bfr[ks][ni], acc[mi][ni], 0, 0, 0);
        __builtin_amdgcn_s_setprio(0);
        if (t + 2 < NKT) {
            asm volatile("s_waitcnt lgkmcnt(0)" ::: "memory");
            __builtin_amdgcn_sched_barrier(0);
            __builtin_amdgcn_s_barrier();
            STAGE(cur, (t + 2) * 64);
            asm volatile("s_waitcnt vmcnt(7)" ::: "memory");
            __builtin_amdgcn_s_barrier();
        } else if (t + 2 == NKT) {
            asm volatile("s_waitcnt vmcnt(0)" ::: "memory");
            __builtin_amdgcn_s_barrier();
        }
    }
    #undef STAGE

    int cr = (lane >> 4) * 4;
    int cc = lane & 15;
    #pragma unroll
    for (int mi = 0; mi < 8; ++mi) {
        #pragma unroll
        for (int ni = 0; ni < 3; ++ni) {
            int rrow = row0 + wr * 128 + mi * 16 + cr;
            int cabs = col0 + wc * 48 + ni * 16 + cc;
            int part = cabs >> 10;
            int cm = cabs & 1023;
            if (part < 2) {
                unsigned short* dst = Pse + (size_t)rrow * 2048 + part * 1024 + cm;
                #pragma unroll
                for (int j = 0; j < 4; ++j) dst[(size_t)j * 2048] = f2bf(acc[mi][ni][j]);
            } else {
                float* dst = Sbuf + (size_t)rrow * M + cm;
                #pragma unroll
                for (int j = 0; j < 4; ++j) dst[(size_t)j * M] = acc[mi][ni][j];
            }
        }
    }
    // ---- chunk totals T (replaces scan1): only part-2 columns ----
    #pragma unroll
    for (int half = 0; half < 2; ++half) {                 // mi group half*4..half*4+3
        int chunk = (row0 >> 6) + wr * 2 + half;
        #pragma unroll
        for (int ni = 0; ni < 3; ++ni) {
            int cabs = col0 + wc * 48 + ni * 16 + cc;
            if (cabs >= 2048) {
                float psum = 0.f;
                #pragma unroll
                for (int mi4 = 0; mi4 < 4; ++mi4) {
                    int mi = half * 4 + mi4;
                    int rbase = row0 + wr * 128 + mi * 16 + cr;
                    #pragma unroll
                    for (int j = 0; j < 4; ++j)
                        psum += ewa[rbase + j] * acc[mi][ni][j];
                }
                psum += __shfl_down(psum, 16);
                psum += __shfl_down(psum, 32);
                if ((lane >> 4) == 0)
                    T[(size_t)chunk * M + (cabs - 2048)] = psum;
            }
        }
    }
}

// ---------------- scan phase 2: exclusive scan of chunk totals (reg-resident) ----------------
__global__ __launch_bounds__(256) void k_scan2(float* __restrict__ T) {
    int m = blockIdx.x * 256 + threadIdx.x;
    float v[NCH];
    #pragma unroll
    for (int c = 0; c < NCH; ++c) v[c] = T[c * M + m];
    float run = 0.f;
    #pragma unroll
    for (int c = 0; c < NCH; ++c) { float t = v[c]; T[c * M + m] = run; run += t; }
}

// ---------------- scan phase 3: in-place inclusive prefix over Sbuf ----------------
__global__ __launch_bounds__(256) void k_scan3(float* __restrict__ Sbuf,
                                               const float* __restrict__ ewa,
                                               const float* __restrict__ T) {
    int m = blockIdx.x * 256 + threadIdx.x;
    int c = blockIdx.y;
    __shared__ float ew[CHUNK];
    if (threadIdx.x < CHUNK) ew[threadIdx.x] = ewa[c * CHUNK + threadIdx.x];
    __syncthreads();
    float acc = T[c * M + m];
    float* base = Sbuf + (size_t)(c * CHUNK) * M + m;
    #pragma unroll 4
    for (int i = 0; i < CHUNK; ++i) {
        float* p = base + (size_t)i * M;
        acc += ew[i] * (*p);
        *p = acc;
    }
}

// ---------------- per-START candidate scoring: one block per start value ----------------
// ps (bf16) and ss (f32) staged in LDS once, shared by all ~12 candidates of the start.
__global__ __launch_bounds__(256) void k_cand(const unsigned short* __restrict__ Pse,
                                              const float* __restrict__ Sbuf,
                                              const float* __restrict__ PW,
                                              const float* __restrict__ Dpre,
                                              const float* __restrict__ wscore,
                                              const int* __restrict__ perm,
                                              const int* __restrict__ begs,
                                              const int* __restrict__ ends,
                                              const float* __restrict__ mlp2_w,
                                              const float* __restrict__ mlp2_b,
                                              float* __restrict__ out) {
    __shared__ __align__(16) unsigned short ps_l[1024];
    __shared__ __align__(16) float ss_l[1024];
    int bid = blockIdx.x;                           // 4096 blocks, %8==0 -> bijective
    int s = (bid & 7) * 512 + (bid >> 3);           // XCD-contiguous start ranges
    int tid = threadIdx.x;
    {
        ushort4 p4 = *reinterpret_cast<const ushort4*>(Pse + (size_t)s * 2048 + tid * 4);
        *reinterpret_cast<ushort4*>(ps_l + tid * 4) = p4;
        float4 s4 = (s > 0) ? *reinterpret_cast<const float4*>(Sbuf + (size_t)(s - 1) * M + tid * 4)
                            : make_float4(0.f, 0.f, 0.f, 0.f);
        *reinterpret_cast<float4*>(ss_l + tid * 4) = s4;
    }
    __syncthreads();
    int beg = begs[s], end = begs[s + 1];
    int wv = tid >> 6, lane = tid & 63;
    float dps = Dpre[s];

    for (int j = beg + wv; j < end; j += 4) {
        int c = perm[j];
        int e = ends[c];
        int wi = e - s;
        wi = wi > MSW - 1 ? MSW - 1 : wi;
        float inv = 1.f / (Dpre[e + 1] - dps);
        const unsigned short* pe = Pse + (size_t)e * 2048 + 1024;
        const float* se = Sbuf + (size_t)e * M;
        const float* pw = PW + (size_t)wi * M;

        float part = 0.f;
        #pragma unroll
        for (int q = 0; q < 2; ++q) {
            int m = lane * 8 + q * 512;
            u16x8 a8 = *reinterpret_cast<const u16x8*>(ps_l + m);
            u16x8 b8 = *reinterpret_cast<const u16x8*>(pe + m);
            float4 t0 = *reinterpret_cast<const float4*>(se + m);
            float4 t1 = *reinterpret_cast<const float4*>(se + m + 4);
            float4 u0 = *reinterpret_cast<const float4*>(ss_l + m);
            float4 u1 = *reinterpret_cast<const float4*>(ss_l + m + 4);
            float4 w0 = *reinterpret_cast<const float4*>(pw + m);
            float4 w1 = *reinterpret_cast<const float4*>(pw + m + 4);
            float4 v0 = *reinterpret_cast<const float4*>(mlp2_w + m);
            float4 v1 = *reinterpret_cast<const float4*>(mlp2_w + m + 4);
            float x;
            x = bf2f(a8[0]) + bf2f(b8[0]) + w0.x + (t0.x - u0.x) * inv; part += fmaxf(x, 0.f) * v0.x;
            x = bf2f(a8[1]) + bf2f(b8[1]) + w0.y + (t0.y - u0.y) * inv; part += fmaxf(x, 0.f) * v0.y;
            x = bf2f(a8[2]) + bf2f(b8[2]) + w0.z + (t0.z - u0.z) * inv; part += fmaxf(x, 0.f) * v0.z;
            x = bf2f(a8[3]) + bf2f(b8[3]) + w0.w + (t0.w - u0.w) * inv; part += fmaxf(x, 0.f) * v0.w;
            x = bf2f(a8[4]) + bf2f(b8[4]) + w1.x + (t1.x - u1.x) * inv; part += fmaxf(x, 0.f) * v1.x;
            x = bf2f(a8[5]) + bf2f(b8[5]) + w1.y + (t1.y - u1.y) * inv; part += fmaxf(x, 0.f) * v1.y;
            x = bf2f(a8[6]) + bf2f(b8[6]) + w1.z + (t1.z - u1.z) * inv; part += fmaxf(x, 0.f) * v1.z;
            x = bf2f(a8[7]) + bf2f(b8[7]) + w1.w + (t1.w - u1.w) * inv; part += fmaxf(x, 0.f) * v1.w;
        }
        #pragma unroll
        for (int off = 32; off > 0; off >>= 1) part += __shfl_down(part, off);
        if (lane == 0) out[c] = part + mlp2_b[0] + wscore[wi];
    }
}

extern "C" void kernel_launch(void* const* d_in, const int* in_sizes, int n_in,
                              void* d_out, int out_size, void* d_ws, size_t ws_size,
                              hipStream_t stream) {
    const float* encoded_doc = (const float*)d_in[0];
    const int*   cand_starts = (const int*)d_in[1];
    const int*   cand_ends   = (const int*)d_in[2];
    const float* width_emb   = (const float*)d_in[3];
    const float* width_prior = (const float*)d_in[4];
    const float* attn_w      = (const float*)d_in[5];
    const float* attn_b      = (const float*)d_in[6];
    const float* mlp1_w      = (const float*)d_in[7];
    const float* mlp1_b      = (const float*)d_in[8];
    const float* mlp2_w      = (const float*)d_in[9];
    const float* mlp2_b      = (const float*)d_in[10];
    const float* wmlp1_w     = (const float*)d_in[11];
    const float* wmlp1_b     = (const float*)d_in[12];
    const float* wmlp2_w     = (const float*)d_in[13];
    const float* wmlp2_b     = (const float*)d_in[14];
    float* out = (float*)d_out;

    // workspace layout (float units from base; all large blocks 16B-aligned)
    float* Sbuf   = (float*)d_ws;                      // NW*1024
    float* T      = Sbuf + (size_t)NW * M;             // NCH*M = 65536
    float* PW     = T + NCH * M;                       // 30*1024
    float* ewa    = PW + MSW * M;                      // 4096
    float* Dpre   = ewa + NW;                          // 4160
    float* wscore = Dpre + 4160;                       // 64
    unsigned short* Pse  = (unsigned short*)(wscore + 64);      // NW*2048 bf16
    unsigned short* docb = Pse + (size_t)NW * 2048;             // NW*H bf16
    unsigned short* Btb  = docb + (size_t)NW * H;               // 3072*H bf16
    int* hist = (int*)(Btb + (size_t)3072 * H);        // 4096
    int* offs = hist + 4096;                           // 4096
    int* begs = offs + 4096;                           // 4097 (pad 4112)
    int* perm = begs + 4112;                           // NC

    k_doc_prep<<<NW / 4, 256, 0, stream>>>(encoded_doc, attn_w, attn_b, docb, ewa, hist);
    k_cvt_bt<<<dim3(H / 32, M / 32, 3), 256, 0, stream>>>(mlp1_w, Btb);
    k_hist<<<NC / 256, 256, 0, stream>>>(cand_starts, hist);
    k_scans2<<<2, 256, 0, stream>>>(ewa, Dpre, hist, offs, begs);
    k_pw_ws<<<dim3(MSW, 5), 256, 0, stream>>>(width_emb, mlp1_w, mlp1_b, PW,
                                              width_prior, wmlp1_w, wmlp1_b,
                                              wmlp2_w, wmlp2_b, wscore);
    k_scatter<<<NC / 256, 256, 0, stream>>>(cand_starts, offs, perm);
    k_proj_mfma<<<256, 512, 0, stream>>>(docb, Btb, ewa, Pse, Sbuf, T);
    k_scan2<<<M / 256, 256, 0, stream>>>(T);
    k_scan3<<<dim3(M / 256, NCH), 256, 0, stream>>>(Sbuf, ewa, T);
    k_cand<<<4096, 256, 0, stream>>>(Pse, Sbuf, PW, Dpre, wscore, perm, begs,
                                     cand_ends, mlp2_w, mlp2_b, out);
}